// Round 1
// baseline (7892.700 us; speedup 1.0000x reference)
//
#include <hip/hip_runtime.h>
#include <hip/hip_fp16.h>

#define DEG 6
#define MD 49
#define RC 10
#define NBATCH 2048
#define FDIM 490
#define HID 4096

// ---------------- Wigner coefficient tables (computed on device each call) ----
// C_l[(mp+l)*n + (m+l))*n + q], n = 2l+1, packed at loff[l].
__global__ void coef_kernel(float* __restrict__ Ctab) {
    int p = blockIdx.x * blockDim.x + threadIdx.x;
    if (p >= 455) return;
    const int poff[8] = {0, 1, 10, 35, 84, 165, 286, 455};
    const int loff[7] = {0, 1, 28, 153, 496, 1225, 2556};
    int l = 0;
    while (p >= poff[l + 1]) ++l;
    int idx = p - poff[l];
    int nn = 2 * l + 1;
    int mpi = idx / nn, mi = idx % nn;
    int mp = mpi - l, m = mi - l;
    double f[13];
    f[0] = 1.0;
    for (int i = 1; i < 13; ++i) f[i] = f[i - 1] * i;
    double pref = sqrt(f[l + mp] * f[l - mp] * f[l + m] * f[l - m]);
    float* row = Ctab + loff[l] + (size_t)(mpi * nn + mi) * nn;
    for (int q = 0; q < nn; ++q) row[q] = 0.f;
    int s0 = max(0, m - mp), s1 = min(l + m, l - mp);
    for (int s = s0; s <= s1; ++s) {
        int q = mp - m + 2 * s;
        double den = f[l + m - s] * f[s] * f[mp - m + s] * f[l - mp - s];
        double t = pref / den;
        if ((mp - m + s) & 1) t = -t;
        row[q] += (float)t;
    }
}

// ---------------- Wigner D + item projection: item[n][490] -------------------
__global__ __launch_bounds__(64) void wigner_kernel(
    const float* __restrict__ angles, const float* __restrict__ item_rep,
    const float* __restrict__ Ctab, float* __restrict__ item) {
    int n = blockIdx.x, lane = threadIdx.x;
    float alpha = angles[n * 3 + 0], beta = angles[n * 3 + 1], gamma = angles[n * 3 + 2];
    float cb = cosf(beta * 0.5f), sb = sinf(beta * 0.5f);
    __shared__ float dsh[169], Dsh[169], Psh[13];
    __shared__ float ear[13], eai[13], egr[13], egi[13];
    const int loff[7] = {0, 1, 28, 153, 496, 1225, 2556};
    const float isq = 0.7071067811865476f;
    for (int l = 0; l <= DEG; ++l) {
        int nn = 2 * l + 1;
        if (lane < nn) {
            int q = lane;
            float pv = 1.f;
            for (int i = 0; i < 2 * l - q; ++i) pv *= cb;
            for (int i = 0; i < q; ++i) pv *= sb;
            Psh[q] = pv;
            float mm = (float)(lane - l);
            float sa, ca; sincosf(alpha * mm, &sa, &ca);
            ear[lane] = ca; eai[lane] = -sa;
            float sg, cg; sincosf(gamma * mm, &sg, &cg);
            egr[lane] = cg; egi[lane] = -sg;
        }
        __syncthreads();
        const float* Cl = Ctab + loff[l];
        for (int e = lane; e < nn * nn; e += 64) {
            float acc = 0.f;
            const float* cr = Cl + e * nn;
            for (int q = 0; q < nn; ++q) acc += cr[q] * Psh[q];
            dsh[e] = acc;
        }
        __syncthreads();
        for (int e = lane; e < nn * nn; e += 64) {
            int u = e / nn, v = e - u * nn;
            // B row u (<=2 nonzeros), complex
            int bn, bi0, bi1; float br0, br1, bm0, bm1;
            int mu = u - l;
            if (mu == 0)      { bn = 1; bi0 = l; br0 = 1.f; bm0 = 0.f; bi1 = 0; br1 = 0.f; bm1 = 0.f; }
            else if (mu > 0)  { bn = 2; bi0 = l + mu; br0 = (mu & 1) ? -isq : isq; bm0 = 0.f;
                                bi1 = l - mu; br1 = isq; bm1 = 0.f; }
            else              { int mm2 = -mu; bn = 2; bi0 = l - mm2; br0 = 0.f; bm0 = isq;
                                bi1 = l + mm2; br1 = 0.f; bm1 = (mm2 & 1) ? isq : -isq; }
            // conj(B) row v
            int cn, ci0, ci1; float cr0, cr1, cm0, cm1;
            int nu = v - l;
            if (nu == 0)      { cn = 1; ci0 = l; cr0 = 1.f; cm0 = 0.f; ci1 = 0; cr1 = 0.f; cm1 = 0.f; }
            else if (nu > 0)  { cn = 2; ci0 = l + nu; cr0 = (nu & 1) ? -isq : isq; cm0 = 0.f;
                                ci1 = l - nu; cr1 = isq; cm1 = 0.f; }
            else              { int mm2 = -nu; cn = 2; ci0 = l - mm2; cr0 = 0.f; cm0 = -isq;
                                ci1 = l + mm2; cr1 = 0.f; cm1 = (mm2 & 1) ? -isq : isq; }
            float acc = 0.f;
            #pragma unroll
            for (int pb = 0; pb < 2; ++pb) {
                if (pb >= bn) break;
                int b = pb ? bi1 : bi0;
                float sr = pb ? br1 : br0, si = pb ? bm1 : bm0;
                float z1r = sr * ear[b] - si * eai[b];
                float z1i = sr * eai[b] + si * ear[b];
                #pragma unroll
                for (int pc = 0; pc < 2; ++pc) {
                    if (pc >= cn) break;
                    int c = pc ? ci1 : ci0;
                    float tr = pc ? cr1 : cr0, ti = pc ? cm1 : cm0;
                    float dv = dsh[b * nn + c];
                    float z2r = egr[c] * tr - egi[c] * ti;
                    float z2i = egr[c] * ti + egi[c] * tr;
                    acc += dv * (z1r * z2r - z1i * z2i);
                }
            }
            Dsh[e] = acc;
        }
        __syncthreads();
        for (int e = lane; e < nn * RC; e += 64) {
            int u = e / RC, r = e - u * RC;
            float acc = 0.f;
            for (int v = 0; v < nn; ++v)
                acc += Dsh[u * nn + v] * item_rep[(l * l + v) * RC + r];
            item[(size_t)n * FDIM + (l * l + u) * RC + r] = acc;
        }
        __syncthreads();
    }
}

// ---------------- FC: item[2048,490] @ W[490,4096] + b, relu -> fp16 ---------
__global__ __launch_bounds__(256) void fc_kernel(
    const float* __restrict__ item, const float* __restrict__ W,
    const float* __restrict__ bias, __half* __restrict__ x0) {
    __shared__ float A[128][36];  // [kk][row], padded: 36*4=144B (16B multiple)
    int tid = threadIdx.x;
    int col0 = blockIdx.x * 128, row0 = blockIdx.y * 32;
    int tx = tid & 63, ty = tid >> 6;
    float acc[8][2];
    #pragma unroll
    for (int j = 0; j < 8; ++j) { acc[j][0] = 0.f; acc[j][1] = 0.f; }
    for (int k0 = 0; k0 < FDIM; k0 += 128) {
        int chunk = min(128, FDIM - k0);
        __syncthreads();
        for (int e = tid; e < 32 * 128; e += 256) {
            int kk = e >> 5, r = e & 31;
            float v = 0.f;
            if (kk < chunk) v = item[(size_t)(row0 + r) * FDIM + k0 + kk];
            A[kk][r] = v;
        }
        __syncthreads();
        for (int kk = 0; kk < chunk; ++kk) {
            float4 a0 = *(const float4*)&A[kk][ty * 8];
            float4 a1 = *(const float4*)&A[kk][ty * 8 + 4];
            float w0 = W[(size_t)(k0 + kk) * HID + col0 + tx];
            float w1 = W[(size_t)(k0 + kk) * HID + col0 + tx + 64];
            float av[8] = {a0.x, a0.y, a0.z, a0.w, a1.x, a1.y, a1.z, a1.w};
            #pragma unroll
            for (int j = 0; j < 8; ++j) {
                acc[j][0] += av[j] * w0;
                acc[j][1] += av[j] * w1;
            }
        }
    }
    float b0v = bias[col0 + tx], b1v = bias[col0 + tx + 64];
    #pragma unroll
    for (int j = 0; j < 8; ++j) {
        int row = row0 + ty * 8 + j;
        float v0 = acc[j][0] + b0v; v0 = v0 > 0.f ? v0 : 0.f;
        float v1 = acc[j][1] + b1v; v1 = v1 > 0.f ? v1 : 0.f;
        x0[(size_t)row * HID + col0 + tx] = __float2half(v0);
        x0[(size_t)row * HID + col0 + tx + 64] = __float2half(v1);
    }
}

// ---------------- conv_transpose (stride2, k4, SAME, no flip), fp32 math -----
// One wave per (n, parity, 4x4 output subtile, <=64 o lanes).
template <int CIN, int COUT, int HIN, bool RELU>
__global__ __launch_bounds__(64) void convt_kernel(
    const __half* __restrict__ X, const float* __restrict__ Kw,
    const float* __restrict__ bias, __half* __restrict__ Y) {
    constexpr int HOUT = HIN * 2;
    constexpr int OL = (COUT < 64) ? COUT : 64;
    constexpr int OEXT = 64 / OL;
    constexpr int BW = 4 * OEXT;
    constexpr int NBT = HIN / BW;
    int lane = threadIdx.x;
    int n = blockIdx.x;
    int z = blockIdx.z;
    int PI = z & 1, PJ = (z >> 1) & 1;
    int tile = z >> 2;
    int ta = tile / NBT, tb = tile % NBT;
    int a0 = ta * 4;
    int o = blockIdx.y * 64 + (lane % OL);
    int b0 = tb * BW + (lane / OL) * 4;
    int rbase = a0 - (PI == 0 ? 1 : 0);
    int cbase = b0 - (PJ == 0 ? 1 : 0);
    const __half* Xn = X + (size_t)n * HIN * HIN * CIN;
    bool rv[5], sv[5];
    #pragma unroll
    for (int t = 0; t < 5; ++t) {
        rv[t] = (unsigned)(rbase + t) < (unsigned)HIN;
        sv[t] = (unsigned)(cbase + t) < (unsigned)HIN;
    }
    float acc[4][4] = {};
    for (int c = 0; c < CIN; c += 2) {
        float xv[5][5][2];
        #pragma unroll
        for (int rr = 0; rr < 5; ++rr)
            #pragma unroll
            for (int ss = 0; ss < 5; ++ss) {
                float vx = 0.f, vy = 0.f;
                if (rv[rr] && sv[ss]) {
                    __half2 h = *(const __half2*)&Xn[((size_t)(rbase + rr) * HIN + (cbase + ss)) * CIN + c];
                    float2 f2 = __half22float2(h);
                    vx = f2.x; vy = f2.y;
                }
                xv[rr][ss][0] = vx; xv[rr][ss][1] = vy;
            }
        #pragma unroll
        for (int t1 = 0; t1 < 2; ++t1)
            #pragma unroll
            for (int t2 = 0; t2 < 2; ++t2) {
                int dh = PI + 2 * t1, dw = PJ + 2 * t2;
                #pragma unroll
                for (int cc = 0; cc < 2; ++cc) {
                    float w = Kw[((size_t)(dh * 4 + dw) * CIN + c + cc) * COUT + o];
                    #pragma unroll
                    for (int a = 0; a < 4; ++a)
                        #pragma unroll
                        for (int b = 0; b < 4; ++b)
                            acc[a][b] += xv[a + t1][b + t2][cc] * w;
                }
            }
    }
    float bv = bias[o];
    #pragma unroll
    for (int a = 0; a < 4; ++a)
        #pragma unroll
        for (int b = 0; b < 4; ++b) {
            int i = 2 * (a0 + a) + PI, j = 2 * (b0 + b) + PJ;
            float v = acc[a][b] + bv;
            if (RELU) v = v > 0.f ? v : 0.f;
            Y[((size_t)(n * HOUT + i) * HOUT + j) * COUT + o] = __float2half(v);
        }
}

// ---------------- final layer: 32ch -> 1ch, 32x32 -> 64x64, writes fp32 ------
__global__ __launch_bounds__(256) void conv4_kernel(
    const __half* __restrict__ X, const float* __restrict__ Kw,
    const float* __restrict__ bias, float* __restrict__ out) {
    int n = blockIdx.x;
    int j = threadIdx.x & 63;
    int i = blockIdx.y * 4 + (threadIdx.x >> 6);
    int a = i >> 1, pi = i & 1;
    int b = j >> 1, pj = j & 1;
    float acc = bias[0];
    const __half* Xn = X + (size_t)n * 32 * 32 * 32;
    #pragma unroll
    for (int t1 = 0; t1 < 2; ++t1) {
        int r = a + t1 - 1 + pi;
        if ((unsigned)r >= 32u) continue;
        #pragma unroll
        for (int t2 = 0; t2 < 2; ++t2) {
            int s = b + t2 - 1 + pj;
            if ((unsigned)s >= 32u) continue;
            int dh = pi + 2 * t1, dw = pj + 2 * t2;
            const __half* xp = &Xn[((size_t)r * 32 + s) * 32];
            const float* wp = &Kw[(dh * 4 + dw) * 32];
            #pragma unroll
            for (int c = 0; c < 32; c += 2) {
                float2 xx = __half22float2(*(const __half2*)&xp[c]);
                acc += xx.x * wp[c] + xx.y * wp[c + 1];
            }
        }
    }
    out[((size_t)n * 64 + i) * 64 + j] = acc;
}

// ---------------- launch -----------------------------------------------------
extern "C" void kernel_launch(void* const* d_in, const int* in_sizes, int n_in,
                              void* d_out, int out_size, void* d_ws, size_t ws_size,
                              hipStream_t stream) {
    const float* angles   = (const float*)d_in[0];
    const float* item_rep = (const float*)d_in[1];
    const float* W        = (const float*)d_in[2];
    const float* bfc      = (const float*)d_in[3];
    const float* k1       = (const float*)d_in[4];
    const float* b1       = (const float*)d_in[5];
    const float* k2       = (const float*)d_in[6];
    const float* b2       = (const float*)d_in[7];
    const float* k3       = (const float*)d_in[8];
    const float* b3       = (const float*)d_in[9];
    const float* k4       = (const float*)d_in[10];
    const float* b4       = (const float*)d_in[11];

    char* ws = (char*)d_ws;
    // ws layout (total ~244 MB): Ctab | item(f32) | x0..x3 (fp16 intermediates)
    float*  Ctab = (float*)(ws + 0);
    float*  item = (float*)(ws + 32768);                  // 2048*490*4 = 4.0 MB
    __half* x0   = (__half*)(ws + 4194304);               // 2048*4096*2   = 16 MB
    __half* x1   = (__half*)(ws + 20971520);              // 2048*8*8*128*2  = 32 MB
    __half* x2   = (__half*)(ws + 54525952);              // 2048*16*16*64*2 = 64 MB
    __half* x3   = (__half*)(ws + 121634816);             // 2048*32*32*32*2 = 128 MB
    float*  out  = (float*)d_out;

    coef_kernel<<<1, 512, 0, stream>>>(Ctab);
    wigner_kernel<<<NBATCH, 64, 0, stream>>>(angles, item_rep, Ctab, item);
    fc_kernel<<<dim3(HID / 128, NBATCH / 32), 256, 0, stream>>>(item, W, bfc, x0);
    // conv1: 4x4x256 -> 8x8x128 ; grid.z = 4 parities * tiles
    convt_kernel<256, 128, 4, true><<<dim3(NBATCH, 2, 4), 64, 0, stream>>>(x0, k1, b1, x1);
    // conv2: 8x8x128 -> 16x16x64
    convt_kernel<128, 64, 8, true><<<dim3(NBATCH, 1, 16), 64, 0, stream>>>(x1, k2, b2, x2);
    // conv3: 16x16x64 -> 32x32x32
    convt_kernel<64, 32, 16, true><<<dim3(NBATCH, 1, 32), 64, 0, stream>>>(x2, k3, b3, x3);
    // conv4: 32x32x32 -> 64x64x1 (no relu), fp32 out
    conv4_kernel<<<dim3(NBATCH, 16), 256, 0, stream>>>(x3, k4, b4, out);
}

// Round 2
// 1114.091 us; speedup vs baseline: 7.0844x; 7.0844x over previous
//
#include <hip/hip_runtime.h>
#include <hip/hip_fp16.h>

#define DEG 6
#define RC 10
#define NBATCH 2048
#define FDIM 490
#define KPAD 512
#define HID 4096

typedef _Float16 f16x8 __attribute__((ext_vector_type(8)));
typedef float f32x4 __attribute__((ext_vector_type(4)));

// ---------------- Wigner coefficient tables (device, each call) --------------
__global__ void coef_kernel(float* __restrict__ Ctab) {
    int p = blockIdx.x * blockDim.x + threadIdx.x;
    if (p >= 455) return;
    const int poff[8] = {0, 1, 10, 35, 84, 165, 286, 455};
    const int loff[7] = {0, 1, 28, 153, 496, 1225, 2556};
    int l = 0;
    while (p >= poff[l + 1]) ++l;
    int idx = p - poff[l];
    int nn = 2 * l + 1;
    int mpi = idx / nn, mi = idx % nn;
    int mp = mpi - l, m = mi - l;
    double f[13];
    f[0] = 1.0;
    for (int i = 1; i < 13; ++i) f[i] = f[i - 1] * i;
    double pref = sqrt(f[l + mp] * f[l - mp] * f[l + m] * f[l - m]);
    float* row = Ctab + loff[l] + (size_t)(mpi * nn + mi) * nn;
    for (int q = 0; q < nn; ++q) row[q] = 0.f;
    int s0 = max(0, m - mp), s1 = min(l + m, l - mp);
    for (int s = s0; s <= s1; ++s) {
        int q = mp - m + 2 * s;
        double den = f[l + m - s] * f[s] * f[mp - m + s] * f[l - mp - s];
        double t = pref / den;
        if ((mp - m + s) & 1) t = -t;
        row[q] += (float)t;
    }
}

// ---------------- Wigner D + item projection -> fp16 item[n][512] ------------
__global__ __launch_bounds__(64) void wigner_kernel(
    const float* __restrict__ angles, const float* __restrict__ item_rep,
    const float* __restrict__ Ctab, __half* __restrict__ item_h) {
    int n = blockIdx.x, lane = threadIdx.x;
    float alpha = angles[n * 3 + 0], beta = angles[n * 3 + 1], gamma = angles[n * 3 + 2];
    float cb = cosf(beta * 0.5f), sb = sinf(beta * 0.5f);
    __shared__ float dsh[169], Dsh[169], Psh[13];
    __shared__ float ear[13], eai[13], egr[13], egi[13];
    const int loff[7] = {0, 1, 28, 153, 496, 1225, 2556};
    const float isq = 0.7071067811865476f;
    for (int l = 0; l <= DEG; ++l) {
        int nn = 2 * l + 1;
        if (lane < nn) {
            int q = lane;
            float pv = 1.f;
            for (int i = 0; i < 2 * l - q; ++i) pv *= cb;
            for (int i = 0; i < q; ++i) pv *= sb;
            Psh[q] = pv;
            float mm = (float)(lane - l);
            float sa, ca; sincosf(alpha * mm, &sa, &ca);
            ear[lane] = ca; eai[lane] = -sa;
            float sg, cg; sincosf(gamma * mm, &sg, &cg);
            egr[lane] = cg; egi[lane] = -sg;
        }
        __syncthreads();
        const float* Cl = Ctab + loff[l];
        for (int e = lane; e < nn * nn; e += 64) {
            float acc = 0.f;
            const float* cr = Cl + e * nn;
            for (int q = 0; q < nn; ++q) acc += cr[q] * Psh[q];
            dsh[e] = acc;
        }
        __syncthreads();
        for (int e = lane; e < nn * nn; e += 64) {
            int u = e / nn, v = e - u * nn;
            int bn, bi0, bi1; float br0, br1, bm0, bm1;
            int mu = u - l;
            if (mu == 0)      { bn = 1; bi0 = l; br0 = 1.f; bm0 = 0.f; bi1 = 0; br1 = 0.f; bm1 = 0.f; }
            else if (mu > 0)  { bn = 2; bi0 = l + mu; br0 = (mu & 1) ? -isq : isq; bm0 = 0.f;
                                bi1 = l - mu; br1 = isq; bm1 = 0.f; }
            else              { int mm2 = -mu; bn = 2; bi0 = l - mm2; br0 = 0.f; bm0 = isq;
                                bi1 = l + mm2; br1 = 0.f; bm1 = (mm2 & 1) ? isq : -isq; }
            int cn, ci0, ci1; float cr0, cr1, cm0, cm1;
            int nu = v - l;
            if (nu == 0)      { cn = 1; ci0 = l; cr0 = 1.f; cm0 = 0.f; ci1 = 0; cr1 = 0.f; cm1 = 0.f; }
            else if (nu > 0)  { cn = 2; ci0 = l + nu; cr0 = (nu & 1) ? -isq : isq; cm0 = 0.f;
                                ci1 = l - nu; cr1 = isq; cm1 = 0.f; }
            else              { int mm2 = -nu; cn = 2; ci0 = l - mm2; cr0 = 0.f; cm0 = -isq;
                                ci1 = l + mm2; cr1 = 0.f; cm1 = (mm2 & 1) ? -isq : isq; }
            float acc = 0.f;
            #pragma unroll
            for (int pb = 0; pb < 2; ++pb) {
                if (pb >= bn) break;
                int b = pb ? bi1 : bi0;
                float sr = pb ? br1 : br0, si = pb ? bm1 : bm0;
                float z1r = sr * ear[b] - si * eai[b];
                float z1i = sr * eai[b] + si * ear[b];
                #pragma unroll
                for (int pc = 0; pc < 2; ++pc) {
                    if (pc >= cn) break;
                    int c = pc ? ci1 : ci0;
                    float tr = pc ? cr1 : cr0, ti = pc ? cm1 : cm0;
                    float dv = dsh[b * nn + c];
                    float z2r = egr[c] * tr - egi[c] * ti;
                    float z2i = egr[c] * ti + egi[c] * tr;
                    acc += dv * (z1r * z2r - z1i * z2i);
                }
            }
            Dsh[e] = acc;
        }
        __syncthreads();
        for (int e = lane; e < nn * RC; e += 64) {
            int u = e / RC, r = e - u * RC;
            float acc = 0.f;
            for (int v = 0; v < nn; ++v)
                acc += Dsh[u * nn + v] * item_rep[(l * l + v) * RC + r];
            item_h[(size_t)n * KPAD + (l * l + u) * RC + r] = __float2half(acc);
        }
        __syncthreads();
    }
    if (lane < KPAD - FDIM)
        item_h[(size_t)n * KPAD + FDIM + lane] = __float2half(0.f);
}

// ---------------- weight prep: W[490,4096] f32 -> Wt[4096][512] f16 ----------
__global__ __launch_bounds__(256) void fcw_prep(const float* __restrict__ W,
                                                __half* __restrict__ Wt) {
    int o = blockIdx.x * blockDim.x + threadIdx.x;
    if (o >= HID) return;
    for (int k0 = 0; k0 < KPAD; k0 += 8) {
        f16x8 v;
        #pragma unroll
        for (int e = 0; e < 8; ++e) {
            int k = k0 + e;
            v[e] = (_Float16)((k < FDIM) ? W[(size_t)k * HID + o] : 0.f);
        }
        *(f16x8*)(Wt + (size_t)o * KPAD + k0) = v;
    }
}

// ---- conv weight prep: K[4][4][CIN][COUT] f32 -> Bt[par][COUT][4*CIN] f16 ---
// k-index inside Bt row: tap*CIN + c, tap = t1*2+t2; dh=pi+2*t1, dw=pj+2*t2.
template <int CIN, int COUT>
__global__ __launch_bounds__(256) void convw_prep(const float* __restrict__ K,
                                                  __half* __restrict__ Bt) {
    int par = blockIdx.x >> 2, tap = blockIdx.x & 3;
    int pi = par & 1, pj = par >> 1;
    int t1 = tap >> 1, t2 = tap & 1;
    int dh = pi + 2 * t1, dw = pj + 2 * t2;
    const float* Ks = K + (size_t)(dh * 4 + dw) * CIN * COUT;
    int o = threadIdx.x % COUT;
    int cg = threadIdx.x / COUT;
    constexpr int NG = 256 / COUT;
    for (int c0 = cg * 8; c0 < CIN; c0 += NG * 8) {
        f16x8 v;
        #pragma unroll
        for (int e = 0; e < 8; ++e) v[e] = (_Float16)Ks[(size_t)(c0 + e) * COUT + o];
        *(f16x8*)(Bt + ((size_t)par * COUT + o) * (4 * CIN) + tap * CIN + c0) = v;
    }
}

// ---------------- FC as MFMA GEMM: [2048x512] x [512x4096] + relu -> f16 -----
__global__ __launch_bounds__(256) void fc_mfma(
    const __half* __restrict__ A, const __half* __restrict__ Wt,
    const float* __restrict__ bias, __half* __restrict__ Y) {
    int lane = threadIdx.x & 63, wid = threadIdx.x >> 6;
    int job = blockIdx.x * 4 + wid;     // 64 jobs, each 32 rows
    int mbase = job * 32;
    int cb = blockIdx.y * 128;          // 32 col blocks of 128
    int klane = (lane >> 4) * 8, coll = lane & 15;
    const __half* pA0 = A + (size_t)(mbase + coll) * KPAD + klane;
    const __half* pB0 = Wt + (size_t)(cb + coll) * KPAD + klane;
    f32x4 acc[2][8] = {};
    for (int s = 0; s < 16; ++s) {
        f16x8 a0 = *(const f16x8*)(pA0 + s * 32);
        f16x8 a1 = *(const f16x8*)(pA0 + 16 * KPAD + s * 32);
        #pragma unroll
        for (int f = 0; f < 8; ++f) {
            f16x8 b = *(const f16x8*)(pB0 + (size_t)f * 16 * KPAD + s * 32);
            acc[0][f] = __builtin_amdgcn_mfma_f32_16x16x32_f16(a0, b, acc[0][f], 0, 0, 0);
            acc[1][f] = __builtin_amdgcn_mfma_f32_16x16x32_f16(a1, b, acc[1][f], 0, 0, 0);
        }
    }
    #pragma unroll
    for (int f = 0; f < 8; ++f) {
        float bv = bias[cb + f * 16 + coll];
        #pragma unroll
        for (int r = 0; r < 2; ++r)
            #pragma unroll
            for (int g = 0; g < 4; ++g) {
                int m = mbase + r * 16 + (lane >> 4) * 4 + g;
                float v = acc[r][f][g] + bv;
                v = v > 0.f ? v : 0.f;
                Y[(size_t)m * HID + cb + f * 16 + coll] = __float2half(v);
            }
    }
}

// ---------------- conv_transpose as per-parity implicit MFMA GEMM ------------
// Y[(n,a,b),o] = sum_{t1,t2,c} X[n, a+t1-1+pi, b+t2-1+pj, c] * Bt[par][o][tap*CIN+c]
template <int CIN, int COUT, int HIN, int R, int LOGH>
__global__ __launch_bounds__(256) void convt_mfma(
    const __half* __restrict__ X, const __half* __restrict__ Bt,
    const float* __restrict__ bias, __half* __restrict__ Y) {
    constexpr int CF = COUT / 16;
    constexpr int HH = HIN * HIN;
    constexpr int KTOT = 4 * CIN;
    constexpr int HOUT = 2 * HIN;
    constexpr int NSTEP = CIN / 32;
    int lane = threadIdx.x & 63, wid = threadIdx.x >> 6;
    int par = blockIdx.y;
    int pi = par & 1, pj = par >> 1;
    int job = blockIdx.x * 4 + wid;
    int posbase = job * (R * 16);
    int klane = (lane >> 4) * 8;
    int coll = lane & 15;

    int nn_[R], aa_[R], bb_[R];
    #pragma unroll
    for (int r = 0; r < R; ++r) {
        int p = posbase + r * 16 + coll;   // A-fragment row = lane&15
        nn_[r] = p >> (2 * LOGH);
        int rem = p & (HH - 1);
        aa_[r] = rem >> LOGH;
        bb_[r] = rem & (HIN - 1);
    }
    const __half* pBf[CF];
    #pragma unroll
    for (int f = 0; f < CF; ++f)
        pBf[f] = Bt + ((size_t)par * COUT + f * 16 + coll) * KTOT + klane;

    f32x4 acc[R][CF] = {};

    #pragma unroll
    for (int tap = 0; tap < 4; ++tap) {
        int t1 = tap >> 1, t2 = tap & 1;
        const __half* pA[R];
        bool va[R];
        #pragma unroll
        for (int r = 0; r < R; ++r) {
            int rr = aa_[r] + t1 - 1 + pi;
            int ss = bb_[r] + t2 - 1 + pj;
            va[r] = ((unsigned)rr < (unsigned)HIN) && ((unsigned)ss < (unsigned)HIN);
            pA[r] = X + ((long)nn_[r] * HH + rr * HIN + ss) * CIN + klane;
        }
        #pragma unroll
        for (int cc = 0; cc < NSTEP; ++cc) {
            f16x8 a[R], b[CF];
            #pragma unroll
            for (int r = 0; r < R; ++r) {
                f16x8 v = {0, 0, 0, 0, 0, 0, 0, 0};
                if (va[r]) v = *(const f16x8*)(pA[r] + cc * 32);
                a[r] = v;
            }
            #pragma unroll
            for (int f = 0; f < CF; ++f)
                b[f] = *(const f16x8*)(pBf[f] + tap * CIN + cc * 32);
            #pragma unroll
            for (int r = 0; r < R; ++r)
                #pragma unroll
                for (int f = 0; f < CF; ++f)
                    acc[r][f] = __builtin_amdgcn_mfma_f32_16x16x32_f16(a[r], b[f], acc[r][f], 0, 0, 0);
        }
    }

    float bv[CF];
    #pragma unroll
    for (int f = 0; f < CF; ++f) bv[f] = bias[f * 16 + coll];

    #pragma unroll
    for (int r = 0; r < R; ++r) {
        #pragma unroll
        for (int g = 0; g < 4; ++g) {
            int p = posbase + r * 16 + (lane >> 4) * 4 + g;  // D row = (lane>>4)*4+g
            int n = p >> (2 * LOGH);
            int rem = p & (HH - 1);
            int a2 = rem >> LOGH, b2 = rem & (HIN - 1);
            size_t ob = (((size_t)n * HOUT + 2 * a2 + pi) * HOUT + 2 * b2 + pj) * COUT;
            #pragma unroll
            for (int f = 0; f < CF; ++f) {
                float v = acc[r][f][g] + bv[f];
                v = v > 0.f ? v : 0.f;
                Y[ob + f * 16 + coll] = __float2half(v);
            }
        }
    }
}

// ---------------- final layer: 32ch -> 1ch, 32x32 -> 64x64, fp32 out ---------
__global__ __launch_bounds__(256) void conv4_kernel(
    const __half* __restrict__ X, const float* __restrict__ Kw,
    const float* __restrict__ bias, float* __restrict__ out) {
    int n = blockIdx.x;
    int j = threadIdx.x & 63;
    int i = blockIdx.y * 4 + (threadIdx.x >> 6);
    int a = i >> 1, pi = i & 1;
    int b = j >> 1, pj = j & 1;
    float acc = bias[0];
    const __half* Xn = X + (size_t)n * 32 * 32 * 32;
    #pragma unroll
    for (int t1 = 0; t1 < 2; ++t1) {
        int r = a + t1 - 1 + pi;
        if ((unsigned)r >= 32u) continue;
        #pragma unroll
        for (int t2 = 0; t2 < 2; ++t2) {
            int s = b + t2 - 1 + pj;
            if ((unsigned)s >= 32u) continue;
            int dh = pi + 2 * t1, dw = pj + 2 * t2;
            const __half* xp = &Xn[((size_t)r * 32 + s) * 32];
            const float* wp = &Kw[(dh * 4 + dw) * 32];
            #pragma unroll
            for (int c = 0; c < 32; c += 2) {
                float2 xx = __half22float2(*(const __half2*)&xp[c]);
                acc += xx.x * wp[c] + xx.y * wp[c + 1];
            }
        }
    }
    out[((size_t)n * 64 + i) * 64 + j] = acc;
}

// ---------------- launch -----------------------------------------------------
extern "C" void kernel_launch(void* const* d_in, const int* in_sizes, int n_in,
                              void* d_out, int out_size, void* d_ws, size_t ws_size,
                              hipStream_t stream) {
    const float* angles   = (const float*)d_in[0];
    const float* item_rep = (const float*)d_in[1];
    const float* W        = (const float*)d_in[2];
    const float* bfc      = (const float*)d_in[3];
    const float* k1       = (const float*)d_in[4];
    const float* b1       = (const float*)d_in[5];
    const float* k2       = (const float*)d_in[6];
    const float* b2       = (const float*)d_in[7];
    const float* k3       = (const float*)d_in[8];
    const float* b3       = (const float*)d_in[9];
    const float* k4       = (const float*)d_in[10];
    const float* b4       = (const float*)d_in[11];

    char* ws = (char*)d_ws;
    // ws layout (same 255,852,544-byte footprint as round 1):
    float*  Ctab  = (float*)(ws + 0);                 //  32 KB
    __half* itemh = (__half*)(ws + 32768);            //   2 MB -> 2,129,920
    __half* Bt1   = (__half*)(ws + 2129920);          //   1 MB -> 3,178,496
    __half* Bt2   = (__half*)(ws + 3178496);          // 256 KB -> 3,440,640
    __half* Bt3   = (__half*)(ws + 3440640);          //  64 KB -> 3,506,176
    __half* x0    = (__half*)(ws + 4194304);          //  16 MB -> 20,971,520
    __half* x1    = (__half*)(ws + 20971520);         //  32 MB -> 54,525,952
    __half* x2    = (__half*)(ws + 54525952);         //  64 MB -> 121,634,816
    __half* x3    = (__half*)(ws + 121634816);        // 128 MB -> 255,852,544
    // Wt_fc (4 MB) aliases the head of x3: it is dead before conv3 writes x3,
    // and is rewritten by fcw_prep at the start of every call (deterministic).
    __half* Wtfc  = (__half*)(ws + 121634816);
    float*  out   = (float*)d_out;

    coef_kernel<<<1, 512, 0, stream>>>(Ctab);
    wigner_kernel<<<NBATCH, 64, 0, stream>>>(angles, item_rep, Ctab, itemh);
    fcw_prep<<<HID / 256, 256, 0, stream>>>(W, Wtfc);
    convw_prep<256, 128><<<16, 256, 0, stream>>>(k1, Bt1);
    convw_prep<128, 64><<<16, 256, 0, stream>>>(k2, Bt2);
    convw_prep<64, 32><<<16, 256, 0, stream>>>(k3, Bt3);

    // FC: 2048x512 @ 512x4096
    fc_mfma<<<dim3(16, 32), 256, 0, stream>>>(itemh, Wtfc, bfc, x0);
    // conv1: 4x4x256 -> 8x8x128   (R=2, CF=8): jobs/par=1024 -> 256 blocks
    convt_mfma<256, 128, 4, 2, 2><<<dim3(256, 4), 256, 0, stream>>>(x0, Bt1, b1, x1);
    // conv2: 8x8x128 -> 16x16x64  (R=4, CF=4): jobs/par=2048 -> 512 blocks
    convt_mfma<128, 64, 8, 4, 3><<<dim3(512, 4), 256, 0, stream>>>(x1, Bt2, b2, x2);
    // conv3: 16x16x64 -> 32x32x32 (R=8, CF=2): jobs/par=4096 -> 1024 blocks
    convt_mfma<64, 32, 16, 8, 4><<<dim3(1024, 4), 256, 0, stream>>>(x2, Bt3, b3, x3);
    // conv4: 32x32x32 -> 64x64x1 (no relu), fp32 out
    conv4_kernel<<<dim3(NBATCH, 16), 256, 0, stream>>>(x3, k4, b4, out);
}

// Round 3
// 826.535 us; speedup vs baseline: 9.5491x; 1.3479x over previous
//
#include <hip/hip_runtime.h>
#include <hip/hip_fp16.h>

#define DEG 6
#define RC 10
#define NBATCH 2048
#define FDIM 490
#define KPAD 512
#define HID 4096

typedef _Float16 f16x8 __attribute__((ext_vector_type(8)));
typedef _Float16 f16x2 __attribute__((ext_vector_type(2)));
typedef float f32x4 __attribute__((ext_vector_type(4)));

__device__ inline float dot2f(f16x2 x, f16x2 w, float acc) {
#if __has_builtin(__builtin_amdgcn_fdot2)
    return __builtin_amdgcn_fdot2(x, w, acc, false);
#else
    return acc + (float)x[0] * (float)w[0] + (float)x[1] * (float)w[1];
#endif
}

// ---------------- Wigner coefficient tables (device, each call) --------------
__global__ void coef_kernel(float* __restrict__ Ctab) {
    int p = blockIdx.x * blockDim.x + threadIdx.x;
    if (p >= 455) return;
    const int poff[8] = {0, 1, 10, 35, 84, 165, 286, 455};
    const int loff[7] = {0, 1, 28, 153, 496, 1225, 2556};
    int l = 0;
    while (p >= poff[l + 1]) ++l;
    int idx = p - poff[l];
    int nn = 2 * l + 1;
    int mpi = idx / nn, mi = idx % nn;
    int mp = mpi - l, m = mi - l;
    double f[13];
    f[0] = 1.0;
    for (int i = 1; i < 13; ++i) f[i] = f[i - 1] * i;
    double pref = sqrt(f[l + mp] * f[l - mp] * f[l + m] * f[l - m]);
    float* row = Ctab + loff[l] + (size_t)(mpi * nn + mi) * nn;
    for (int q = 0; q < nn; ++q) row[q] = 0.f;
    int s0 = max(0, m - mp), s1 = min(l + m, l - mp);
    for (int s = s0; s <= s1; ++s) {
        int q = mp - m + 2 * s;
        double den = f[l + m - s] * f[s] * f[mp - m + s] * f[l - mp - s];
        double t = pref / den;
        if ((mp - m + s) & 1) t = -t;
        row[q] += (float)t;
    }
}

// ---------------- Wigner D + item projection -> fp16 item[n][512] ------------
__global__ __launch_bounds__(64) void wigner_kernel(
    const float* __restrict__ angles, const float* __restrict__ item_rep,
    const float* __restrict__ Ctab, __half* __restrict__ item_h) {
    int n = blockIdx.x, lane = threadIdx.x;
    float alpha = angles[n * 3 + 0], beta = angles[n * 3 + 1], gamma = angles[n * 3 + 2];
    float cb = cosf(beta * 0.5f), sb = sinf(beta * 0.5f);
    __shared__ float dsh[169], Dsh[169], Psh[13];
    __shared__ float ear[13], eai[13], egr[13], egi[13];
    const int loff[7] = {0, 1, 28, 153, 496, 1225, 2556};
    const float isq = 0.7071067811865476f;
    for (int l = 0; l <= DEG; ++l) {
        int nn = 2 * l + 1;
        if (lane < nn) {
            int q = lane;
            float pv = 1.f;
            for (int i = 0; i < 2 * l - q; ++i) pv *= cb;
            for (int i = 0; i < q; ++i) pv *= sb;
            Psh[q] = pv;
            float mm = (float)(lane - l);
            float sa, ca; sincosf(alpha * mm, &sa, &ca);
            ear[lane] = ca; eai[lane] = -sa;
            float sg, cg; sincosf(gamma * mm, &sg, &cg);
            egr[lane] = cg; egi[lane] = -sg;
        }
        __syncthreads();
        const float* Cl = Ctab + loff[l];
        for (int e = lane; e < nn * nn; e += 64) {
            float acc = 0.f;
            const float* cr = Cl + e * nn;
            for (int q = 0; q < nn; ++q) acc += cr[q] * Psh[q];
            dsh[e] = acc;
        }
        __syncthreads();
        for (int e = lane; e < nn * nn; e += 64) {
            int u = e / nn, v = e - u * nn;
            int bn, bi0, bi1; float br0, br1, bm0, bm1;
            int mu = u - l;
            if (mu == 0)      { bn = 1; bi0 = l; br0 = 1.f; bm0 = 0.f; bi1 = 0; br1 = 0.f; bm1 = 0.f; }
            else if (mu > 0)  { bn = 2; bi0 = l + mu; br0 = (mu & 1) ? -isq : isq; bm0 = 0.f;
                                bi1 = l - mu; br1 = isq; bm1 = 0.f; }
            else              { int mm2 = -mu; bn = 2; bi0 = l - mm2; br0 = 0.f; bm0 = isq;
                                bi1 = l + mm2; br1 = 0.f; bm1 = (mm2 & 1) ? isq : -isq; }
            int cn, ci0, ci1; float cr0, cr1, cm0, cm1;
            int nu = v - l;
            if (nu == 0)      { cn = 1; ci0 = l; cr0 = 1.f; cm0 = 0.f; ci1 = 0; cr1 = 0.f; cm1 = 0.f; }
            else if (nu > 0)  { cn = 2; ci0 = l + nu; cr0 = (nu & 1) ? -isq : isq; cm0 = 0.f;
                                ci1 = l - nu; cr1 = isq; cm1 = 0.f; }
            else              { int mm2 = -nu; cn = 2; ci0 = l - mm2; cr0 = 0.f; cm0 = -isq;
                                ci1 = l + mm2; cr1 = 0.f; cm1 = (mm2 & 1) ? -isq : isq; }
            float acc = 0.f;
            #pragma unroll
            for (int pb = 0; pb < 2; ++pb) {
                if (pb >= bn) break;
                int b = pb ? bi1 : bi0;
                float sr = pb ? br1 : br0, si = pb ? bm1 : bm0;
                float z1r = sr * ear[b] - si * eai[b];
                float z1i = sr * eai[b] + si * ear[b];
                #pragma unroll
                for (int pc = 0; pc < 2; ++pc) {
                    if (pc >= cn) break;
                    int c = pc ? ci1 : ci0;
                    float tr = pc ? cr1 : cr0, ti = pc ? cm1 : cm0;
                    float dv = dsh[b * nn + c];
                    float z2r = egr[c] * tr - egi[c] * ti;
                    float z2i = egr[c] * ti + egi[c] * tr;
                    acc += dv * (z1r * z2r - z1i * z2i);
                }
            }
            Dsh[e] = acc;
        }
        __syncthreads();
        for (int e = lane; e < nn * RC; e += 64) {
            int u = e / RC, r = e - u * RC;
            float acc = 0.f;
            for (int v = 0; v < nn; ++v)
                acc += Dsh[u * nn + v] * item_rep[(l * l + v) * RC + r];
            item_h[(size_t)n * KPAD + (l * l + u) * RC + r] = __float2half(acc);
        }
        __syncthreads();
    }
    if (lane < KPAD - FDIM)
        item_h[(size_t)n * KPAD + FDIM + lane] = __float2half(0.f);
}

// ---------------- weight prep: W[490,4096] f32 -> Wt[4096][512] f16 ----------
__global__ __launch_bounds__(256) void fcw_prep(const float* __restrict__ W,
                                                __half* __restrict__ Wt) {
    int o = blockIdx.x * blockDim.x + threadIdx.x;
    if (o >= HID) return;
    for (int k0 = 0; k0 < KPAD; k0 += 8) {
        f16x8 v;
        #pragma unroll
        for (int e = 0; e < 8; ++e) {
            int k = k0 + e;
            v[e] = (_Float16)((k < FDIM) ? W[(size_t)k * HID + o] : 0.f);
        }
        *(f16x8*)(Wt + (size_t)o * KPAD + k0) = v;
    }
}

// ---- conv weight prep: K[4][4][CIN][COUT] f32 -> Bt[par][COUT][4*CIN] f16 ---
template <int CIN, int COUT>
__global__ __launch_bounds__(256) void convw_prep(const float* __restrict__ K,
                                                  __half* __restrict__ Bt) {
    int par = blockIdx.x >> 2, tap = blockIdx.x & 3;
    int pi = par & 1, pj = par >> 1;
    int t1 = tap >> 1, t2 = tap & 1;
    int dh = pi + 2 * t1, dw = pj + 2 * t2;
    const float* Ks = K + (size_t)(dh * 4 + dw) * CIN * COUT;
    int o = threadIdx.x % COUT;
    int cg = threadIdx.x / COUT;
    constexpr int NG = 256 / COUT;
    for (int c0 = cg * 8; c0 < CIN; c0 += NG * 8) {
        f16x8 v;
        #pragma unroll
        for (int e = 0; e < 8; ++e) v[e] = (_Float16)Ks[(size_t)(c0 + e) * COUT + o];
        *(f16x8*)(Bt + ((size_t)par * COUT + o) * (4 * CIN) + tap * CIN + c0) = v;
    }
}

// ---- conv4 weight prep: K[4][4][32][1] f32 -> f16 [16][32] ------------------
__global__ __launch_bounds__(256) void conv4w_prep(const float* __restrict__ K,
                                                   __half* __restrict__ Kh) {
    int t = blockIdx.x * blockDim.x + threadIdx.x;
    if (t < 512) Kh[t] = __float2half(K[t]);
}

// ---------------- FC as MFMA GEMM: [2048x512] x [512x4096] + relu -> f16 -----
__global__ __launch_bounds__(256) void fc_mfma(
    const __half* __restrict__ A, const __half* __restrict__ Wt,
    const float* __restrict__ bias, __half* __restrict__ Y) {
    int lane = threadIdx.x & 63, wid = threadIdx.x >> 6;
    int job = blockIdx.x * 4 + wid;
    int mbase = job * 32;
    int cb = blockIdx.y * 128;
    int klane = (lane >> 4) * 8, coll = lane & 15;
    const __half* pA0 = A + (size_t)(mbase + coll) * KPAD + klane;
    const __half* pB0 = Wt + (size_t)(cb + coll) * KPAD + klane;
    f32x4 acc[2][8] = {};
    for (int s = 0; s < 16; ++s) {
        f16x8 a0 = *(const f16x8*)(pA0 + s * 32);
        f16x8 a1 = *(const f16x8*)(pA0 + 16 * KPAD + s * 32);
        #pragma unroll
        for (int f = 0; f < 8; ++f) {
            f16x8 b = *(const f16x8*)(pB0 + (size_t)f * 16 * KPAD + s * 32);
            acc[0][f] = __builtin_amdgcn_mfma_f32_16x16x32_f16(a0, b, acc[0][f], 0, 0, 0);
            acc[1][f] = __builtin_amdgcn_mfma_f32_16x16x32_f16(a1, b, acc[1][f], 0, 0, 0);
        }
    }
    #pragma unroll
    for (int f = 0; f < 8; ++f) {
        float bv = bias[cb + f * 16 + coll];
        #pragma unroll
        for (int r = 0; r < 2; ++r)
            #pragma unroll
            for (int g = 0; g < 4; ++g) {
                int m = mbase + r * 16 + (lane >> 4) * 4 + g;
                float v = acc[r][f][g] + bv;
                v = v > 0.f ? v : 0.f;
                Y[(size_t)m * HID + cb + f * 16 + coll] = __float2half(v);
            }
    }
}

// ---------------- conv_transpose as per-parity implicit MFMA GEMM ------------
// OH = output image height incl. padding; OB = border offset (pad shift).
template <int CIN, int COUT, int HIN, int R, int LOGH, int OH, int OB>
__global__ __launch_bounds__(256) void convt_mfma(
    const __half* __restrict__ X, const __half* __restrict__ Bt,
    const float* __restrict__ bias, __half* __restrict__ Y) {
    constexpr int CF = COUT / 16;
    constexpr int HH = HIN * HIN;
    constexpr int KTOT = 4 * CIN;
    constexpr int NSTEP = CIN / 32;
    int lane = threadIdx.x & 63, wid = threadIdx.x >> 6;
    int par = blockIdx.y;
    int pi = par & 1, pj = par >> 1;
    int job = blockIdx.x * 4 + wid;
    int posbase = job * (R * 16);
    int klane = (lane >> 4) * 8;
    int coll = lane & 15;

    int nn_[R], aa_[R], bb_[R];
    #pragma unroll
    for (int r = 0; r < R; ++r) {
        int p = posbase + r * 16 + coll;
        nn_[r] = p >> (2 * LOGH);
        int rem = p & (HH - 1);
        aa_[r] = rem >> LOGH;
        bb_[r] = rem & (HIN - 1);
    }
    const __half* pBf[CF];
    #pragma unroll
    for (int f = 0; f < CF; ++f)
        pBf[f] = Bt + ((size_t)par * COUT + f * 16 + coll) * KTOT + klane;

    f32x4 acc[R][CF] = {};

    #pragma unroll
    for (int tap = 0; tap < 4; ++tap) {
        int t1 = tap >> 1, t2 = tap & 1;
        const __half* pA[R];
        bool va[R];
        #pragma unroll
        for (int r = 0; r < R; ++r) {
            int rr = aa_[r] + t1 - 1 + pi;
            int ss = bb_[r] + t2 - 1 + pj;
            va[r] = ((unsigned)rr < (unsigned)HIN) && ((unsigned)ss < (unsigned)HIN);
            pA[r] = X + ((long)nn_[r] * HH + rr * HIN + ss) * CIN + klane;
        }
        #pragma unroll
        for (int cc = 0; cc < NSTEP; ++cc) {
            f16x8 a[R], b[CF];
            #pragma unroll
            for (int r = 0; r < R; ++r) {
                f16x8 v = {0, 0, 0, 0, 0, 0, 0, 0};
                if (va[r]) v = *(const f16x8*)(pA[r] + cc * 32);
                a[r] = v;
            }
            #pragma unroll
            for (int f = 0; f < CF; ++f)
                b[f] = *(const f16x8*)(pBf[f] + tap * CIN + cc * 32);
            #pragma unroll
            for (int r = 0; r < R; ++r)
                #pragma unroll
                for (int f = 0; f < CF; ++f)
                    acc[r][f] = __builtin_amdgcn_mfma_f32_16x16x32_f16(a[r], b[f], acc[r][f], 0, 0, 0);
        }
    }

    float bv[CF];
    #pragma unroll
    for (int f = 0; f < CF; ++f) bv[f] = bias[f * 16 + coll];

    #pragma unroll
    for (int r = 0; r < R; ++r) {
        #pragma unroll
        for (int g = 0; g < 4; ++g) {
            int p = posbase + r * 16 + (lane >> 4) * 4 + g;
            int n = p >> (2 * LOGH);
            int rem = p & (HH - 1);
            int a2 = rem >> LOGH, b2 = rem & (HIN - 1);
            size_t ob = (((size_t)n * OH + 2 * a2 + pi + OB) * OH + 2 * b2 + pj + OB) * COUT;
            #pragma unroll
            for (int f = 0; f < CF; ++f) {
                float v = acc[r][f][g] + bv[f];
                v = v > 0.f ? v : 0.f;
                Y[ob + f * 16 + coll] = __float2half(v);
            }
        }
    }
}

// ---------------- zero the 1-wide border ring of padded x3 -------------------
__global__ __launch_bounds__(256) void pad_zero(__half* __restrict__ Xp) {
    int n = blockIdx.x;
    __half* base = Xp + (size_t)n * 34 * 34 * 32;
    for (int w = threadIdx.x; w < 132 * 4; w += 256) {
        int posi = w >> 2, q = w & 3;
        int r, s;
        if (posi < 68) { r = (posi < 34) ? 0 : 33; s = posi % 34; }
        else { int e = posi - 68; r = 1 + (e >> 1); s = (e & 1) ? 33 : 0; }
        *(f16x8*)(base + ((size_t)r * 34 + s) * 32 + q * 8) = (f16x8){0, 0, 0, 0, 0, 0, 0, 0};
    }
}

// ---------------- conv4: padded 34x34x32 -> 64x64x1, fp32 out ----------------
// One thread = one (a,b) site = 4 output parities; 3x3x32 window loaded once.
__global__ __launch_bounds__(256) void conv4_kernel2(
    const __half* __restrict__ Xp, const __half* __restrict__ Wh,
    const float* __restrict__ bias, float* __restrict__ out) {
    int n = blockIdx.x;
    int t = threadIdx.x;
    int b = t & 31;
    int a = (blockIdx.y << 3) + (t >> 5);
    const __half* Xn = Xp + (size_t)n * 34 * 34 * 32;
    const f16x2* W2 = (const f16x2*)Wh;
    float a00 = 0.f, a01 = 0.f, a10 = 0.f, a11 = 0.f;
    #pragma unroll
    for (int hf = 0; hf < 2; ++hf) {
        f16x2 xw[9][8];
        #pragma unroll
        for (int u = 0; u < 3; ++u)
            #pragma unroll
            for (int v = 0; v < 3; ++v) {
                const f16x8* p = (const f16x8*)(Xn + ((size_t)(a + u) * 34 + (b + v)) * 32 + hf * 16);
                f16x8 lo = p[0], hi = p[1];
                #pragma unroll
                for (int e = 0; e < 4; ++e) {
                    xw[u * 3 + v][e]     = (f16x2){lo[2 * e], lo[2 * e + 1]};
                    xw[u * 3 + v][e + 4] = (f16x2){hi[2 * e], hi[2 * e + 1]};
                }
            }
        #pragma unroll
        for (int pi = 0; pi < 2; ++pi)
            #pragma unroll
            for (int pj = 0; pj < 2; ++pj) {
                float acc = pi ? (pj ? a11 : a10) : (pj ? a01 : a00);
                #pragma unroll
                for (int t1 = 0; t1 < 2; ++t1)
                    #pragma unroll
                    for (int t2 = 0; t2 < 2; ++t2) {
                        int pos = (pi + t1) * 3 + (pj + t2);
                        const f16x2* wrow = W2 + ((pi + 2 * t1) * 4 + (pj + 2 * t2)) * 16 + hf * 8;
                        #pragma unroll
                        for (int e = 0; e < 8; ++e)
                            acc = dot2f(xw[pos][e], wrow[e], acc);
                    }
                if (pi) { if (pj) a11 = acc; else a10 = acc; }
                else    { if (pj) a01 = acc; else a00 = acc; }
            }
    }
    float bv = bias[0];
    out[((size_t)n * 64 + 2 * a + 0) * 64 + 2 * b + 0] = a00 + bv;
    out[((size_t)n * 64 + 2 * a + 0) * 64 + 2 * b + 1] = a01 + bv;
    out[((size_t)n * 64 + 2 * a + 1) * 64 + 2 * b + 0] = a10 + bv;
    out[((size_t)n * 64 + 2 * a + 1) * 64 + 2 * b + 1] = a11 + bv;
}

// ---------------- launch -----------------------------------------------------
extern "C" void kernel_launch(void* const* d_in, const int* in_sizes, int n_in,
                              void* d_out, int out_size, void* d_ws, size_t ws_size,
                              hipStream_t stream) {
    const float* angles   = (const float*)d_in[0];
    const float* item_rep = (const float*)d_in[1];
    const float* W        = (const float*)d_in[2];
    const float* bfc      = (const float*)d_in[3];
    const float* k1       = (const float*)d_in[4];
    const float* b1       = (const float*)d_in[5];
    const float* k2       = (const float*)d_in[6];
    const float* b2       = (const float*)d_in[7];
    const float* k3       = (const float*)d_in[8];
    const float* b3       = (const float*)d_in[9];
    const float* k4       = (const float*)d_in[10];
    const float* b4       = (const float*)d_in[11];

    char* ws = (char*)d_ws;
    // ws layout (max offset 222,822,400 — below round-1's proven 255,852,544):
    //   x3p (padded 2048x34x34x32 f16, 151.5 MB) aliases dead x0+x1+Wtfc;
    //   write order: fc->x0, conv1->x1, conv2->x2, pad_zero+conv3->x3p, conv4.
    float*  Ctab  = (float*)(ws + 0);                 //  32 KB
    __half* itemh = (__half*)(ws + 32768);            //   2 MB
    __half* Bt1   = (__half*)(ws + 2129920);          //   1 MB
    __half* Bt2   = (__half*)(ws + 3178496);          // 256 KB
    __half* Bt3   = (__half*)(ws + 3440640);          //  64 KB
    __half* Kh4   = (__half*)(ws + 3506176);          //   1 KB
    __half* x0    = (__half*)(ws + 4194304);          //  16 MB -> 20,971,520
    __half* x1    = (__half*)(ws + 20971520);         //  32 MB -> 54,525,952
    __half* x3p   = (__half*)(ws + 4194304);          // 151.5 MB -> 155,713,536
    __half* Wtfc  = (__half*)(ws + 121634816);        //   4 MB (inside x3p, dead by conv3)
    __half* x2    = (__half*)(ws + 155713536);        //  64 MB -> 222,822,400
    float*  out   = (float*)d_out;

    coef_kernel<<<1, 512, 0, stream>>>(Ctab);
    wigner_kernel<<<NBATCH, 64, 0, stream>>>(angles, item_rep, Ctab, itemh);
    fcw_prep<<<HID / 256, 256, 0, stream>>>(W, Wtfc);
    convw_prep<256, 128><<<16, 256, 0, stream>>>(k1, Bt1);
    convw_prep<128, 64><<<16, 256, 0, stream>>>(k2, Bt2);
    convw_prep<64, 32><<<16, 256, 0, stream>>>(k3, Bt3);
    conv4w_prep<<<2, 256, 0, stream>>>(k4, Kh4);

    // FC: 2048x512 @ 512x4096 -> x0
    fc_mfma<<<dim3(16, 32), 256, 0, stream>>>(itemh, Wtfc, bfc, x0);
    // conv1: 4x4x256 -> 8x8x128
    convt_mfma<256, 128, 4, 2, 2, 8, 0><<<dim3(256, 4), 256, 0, stream>>>(x0, Bt1, b1, x1);
    // conv2: 8x8x128 -> 16x16x64
    convt_mfma<128, 64, 8, 4, 3, 16, 0><<<dim3(512, 4), 256, 0, stream>>>(x1, Bt2, b2, x2);
    // zero x3p border ring, then conv3 writes the 32x32 interior at +1
    pad_zero<<<NBATCH, 256, 0, stream>>>(x3p);
    // conv3: 16x16x64 -> (34x34 padded)x32
    convt_mfma<64, 32, 16, 8, 4, 34, 1><<<dim3(1024, 4), 256, 0, stream>>>(x2, Bt3, b3, x3p);
    // conv4: padded 34x34x32 -> 64x64x1 (fp32 out)
    conv4_kernel2<<<dim3(NBATCH, 4), 256, 0, stream>>>(x3p, Kh4, b4, out);
}

// Round 4
// 791.397 us; speedup vs baseline: 9.9731x; 1.0444x over previous
//
#include <hip/hip_runtime.h>
#include <hip/hip_fp16.h>

#define DEG 6
#define RC 10
#define NBATCH 2048
#define FDIM 490
#define KPAD 512
#define HID 4096

typedef _Float16 f16x8 __attribute__((ext_vector_type(8)));
typedef _Float16 f16x2 __attribute__((ext_vector_type(2)));
typedef float f32x4 __attribute__((ext_vector_type(4)));

__device__ inline float dot2f(f16x2 x, f16x2 w, float acc) {
#if __has_builtin(__builtin_amdgcn_fdot2)
    return __builtin_amdgcn_fdot2(x, w, acc, false);
#else
    return acc + (float)x[0] * (float)w[0] + (float)x[1] * (float)w[1];
#endif
}

// ---------------- Wigner coefficient tables (device, each call) --------------
__global__ void coef_kernel(float* __restrict__ Ctab) {
    int p = blockIdx.x * blockDim.x + threadIdx.x;
    if (p >= 455) return;
    const int poff[8] = {0, 1, 10, 35, 84, 165, 286, 455};
    const int loff[7] = {0, 1, 28, 153, 496, 1225, 2556};
    int l = 0;
    while (p >= poff[l + 1]) ++l;
    int idx = p - poff[l];
    int nn = 2 * l + 1;
    int mpi = idx / nn, mi = idx % nn;
    int mp = mpi - l, m = mi - l;
    double f[13];
    f[0] = 1.0;
    for (int i = 1; i < 13; ++i) f[i] = f[i - 1] * i;
    double pref = sqrt(f[l + mp] * f[l - mp] * f[l + m] * f[l - m]);
    float* row = Ctab + loff[l] + (size_t)(mpi * nn + mi) * nn;
    for (int q = 0; q < nn; ++q) row[q] = 0.f;
    int s0 = max(0, m - mp), s1 = min(l + m, l - mp);
    for (int s = s0; s <= s1; ++s) {
        int q = mp - m + 2 * s;
        double den = f[l + m - s] * f[s] * f[mp - m + s] * f[l - mp - s];
        double t = pref / den;
        if ((mp - m + s) & 1) t = -t;
        row[q] += (float)t;
    }
}

// ---------------- Wigner D + item projection -> fp16 item[n][512] ------------
__global__ __launch_bounds__(64) void wigner_kernel(
    const float* __restrict__ angles, const float* __restrict__ item_rep,
    const float* __restrict__ Ctab, __half* __restrict__ item_h) {
    int n = blockIdx.x, lane = threadIdx.x;
    float alpha = angles[n * 3 + 0], beta = angles[n * 3 + 1], gamma = angles[n * 3 + 2];
    float cb = cosf(beta * 0.5f), sb = sinf(beta * 0.5f);
    __shared__ float dsh[169], Dsh[169], Psh[13];
    __shared__ float ear[13], eai[13], egr[13], egi[13];
    const int loff[7] = {0, 1, 28, 153, 496, 1225, 2556};
    const float isq = 0.7071067811865476f;
    for (int l = 0; l <= DEG; ++l) {
        int nn = 2 * l + 1;
        if (lane < nn) {
            int q = lane;
            float pv = 1.f;
            for (int i = 0; i < 2 * l - q; ++i) pv *= cb;
            for (int i = 0; i < q; ++i) pv *= sb;
            Psh[q] = pv;
            float mm = (float)(lane - l);
            float sa, ca; sincosf(alpha * mm, &sa, &ca);
            ear[lane] = ca; eai[lane] = -sa;
            float sg, cg; sincosf(gamma * mm, &sg, &cg);
            egr[lane] = cg; egi[lane] = -sg;
        }
        __syncthreads();
        const float* Cl = Ctab + loff[l];
        for (int e = lane; e < nn * nn; e += 64) {
            float acc = 0.f;
            const float* cr = Cl + e * nn;
            for (int q = 0; q < nn; ++q) acc += cr[q] * Psh[q];
            dsh[e] = acc;
        }
        __syncthreads();
        for (int e = lane; e < nn * nn; e += 64) {
            int u = e / nn, v = e - u * nn;
            int bn, bi0, bi1; float br0, br1, bm0, bm1;
            int mu = u - l;
            if (mu == 0)      { bn = 1; bi0 = l; br0 = 1.f; bm0 = 0.f; bi1 = 0; br1 = 0.f; bm1 = 0.f; }
            else if (mu > 0)  { bn = 2; bi0 = l + mu; br0 = (mu & 1) ? -isq : isq; bm0 = 0.f;
                                bi1 = l - mu; br1 = isq; bm1 = 0.f; }
            else              { int mm2 = -mu; bn = 2; bi0 = l - mm2; br0 = 0.f; bm0 = isq;
                                bi1 = l + mm2; br1 = 0.f; bm1 = (mm2 & 1) ? isq : -isq; }
            int cn, ci0, ci1; float cr0, cr1, cm0, cm1;
            int nu = v - l;
            if (nu == 0)      { cn = 1; ci0 = l; cr0 = 1.f; cm0 = 0.f; ci1 = 0; cr1 = 0.f; cm1 = 0.f; }
            else if (nu > 0)  { cn = 2; ci0 = l + nu; cr0 = (nu & 1) ? -isq : isq; cm0 = 0.f;
                                ci1 = l - nu; cr1 = isq; cm1 = 0.f; }
            else              { int mm2 = -nu; cn = 2; ci0 = l - mm2; cr0 = 0.f; cm0 = -isq;
                                ci1 = l + mm2; cr1 = 0.f; cm1 = (mm2 & 1) ? -isq : isq; }
            float acc = 0.f;
            #pragma unroll
            for (int pb = 0; pb < 2; ++pb) {
                if (pb >= bn) break;
                int b = pb ? bi1 : bi0;
                float sr = pb ? br1 : br0, si = pb ? bm1 : bm0;
                float z1r = sr * ear[b] - si * eai[b];
                float z1i = sr * eai[b] + si * ear[b];
                #pragma unroll
                for (int pc = 0; pc < 2; ++pc) {
                    if (pc >= cn) break;
                    int c = pc ? ci1 : ci0;
                    float tr = pc ? cr1 : cr0, ti = pc ? cm1 : cm0;
                    float dv = dsh[b * nn + c];
                    float z2r = egr[c] * tr - egi[c] * ti;
                    float z2i = egr[c] * ti + egi[c] * tr;
                    acc += dv * (z1r * z2r - z1i * z2i);
                }
            }
            Dsh[e] = acc;
        }
        __syncthreads();
        for (int e = lane; e < nn * RC; e += 64) {
            int u = e / RC, r = e - u * RC;
            float acc = 0.f;
            for (int v = 0; v < nn; ++v)
                acc += Dsh[u * nn + v] * item_rep[(l * l + v) * RC + r];
            item_h[(size_t)n * KPAD + (l * l + u) * RC + r] = __float2half(acc);
        }
        __syncthreads();
    }
    if (lane < KPAD - FDIM)
        item_h[(size_t)n * KPAD + FDIM + lane] = __float2half(0.f);
}

// ---------------- weight prep: W[490,4096] f32 -> Wt[4096][512] f16 ----------
__global__ __launch_bounds__(256) void fcw_prep(const float* __restrict__ W,
                                                __half* __restrict__ Wt) {
    int o = blockIdx.x * blockDim.x + threadIdx.x;
    if (o >= HID) return;
    for (int k0 = 0; k0 < KPAD; k0 += 8) {
        f16x8 v;
        #pragma unroll
        for (int e = 0; e < 8; ++e) {
            int k = k0 + e;
            v[e] = (_Float16)((k < FDIM) ? W[(size_t)k * HID + o] : 0.f);
        }
        *(f16x8*)(Wt + (size_t)o * KPAD + k0) = v;
    }
}

// ---- conv weight prep: K[4][4][CIN][COUT] f32 -> Bt[par][COUT][4*CIN] f16 ---
template <int CIN, int COUT>
__global__ __launch_bounds__(256) void convw_prep(const float* __restrict__ K,
                                                  __half* __restrict__ Bt) {
    int par = blockIdx.x >> 2, tap = blockIdx.x & 3;
    int pi = par & 1, pj = par >> 1;
    int t1 = tap >> 1, t2 = tap & 1;
    int dh = pi + 2 * t1, dw = pj + 2 * t2;
    const float* Ks = K + (size_t)(dh * 4 + dw) * CIN * COUT;
    int o = threadIdx.x % COUT;
    int cg = threadIdx.x / COUT;
    constexpr int NG = 256 / COUT;
    for (int c0 = cg * 8; c0 < CIN; c0 += NG * 8) {
        f16x8 v;
        #pragma unroll
        for (int e = 0; e < 8; ++e) v[e] = (_Float16)Ks[(size_t)(c0 + e) * COUT + o];
        *(f16x8*)(Bt + ((size_t)par * COUT + o) * (4 * CIN) + tap * CIN + c0) = v;
    }
}

// ---- conv4 weight prep: K[4][4][32][1] f32 -> f16 [16][32] ------------------
__global__ __launch_bounds__(256) void conv4w_prep(const float* __restrict__ K,
                                                   __half* __restrict__ Kh) {
    int t = blockIdx.x * blockDim.x + threadIdx.x;
    if (t < 512) Kh[t] = __float2half(K[t]);
}

// ---------------- FC as MFMA GEMM: [2048x512] x [512x4096] + relu -> f16 -----
__global__ __launch_bounds__(256) void fc_mfma(
    const __half* __restrict__ A, const __half* __restrict__ Wt,
    const float* __restrict__ bias, __half* __restrict__ Y) {
    int lane = threadIdx.x & 63, wid = threadIdx.x >> 6;
    int job = blockIdx.x * 4 + wid;
    int mbase = job * 32;
    int cb = blockIdx.y * 128;
    int klane = (lane >> 4) * 8, coll = lane & 15;
    const __half* pA0 = A + (size_t)(mbase + coll) * KPAD + klane;
    const __half* pB0 = Wt + (size_t)(cb + coll) * KPAD + klane;
    f32x4 acc[2][8] = {};
    for (int s = 0; s < 16; ++s) {
        f16x8 a0 = *(const f16x8*)(pA0 + s * 32);
        f16x8 a1 = *(const f16x8*)(pA0 + 16 * KPAD + s * 32);
        #pragma unroll
        for (int f = 0; f < 8; ++f) {
            f16x8 b = *(const f16x8*)(pB0 + (size_t)f * 16 * KPAD + s * 32);
            acc[0][f] = __builtin_amdgcn_mfma_f32_16x16x32_f16(a0, b, acc[0][f], 0, 0, 0);
            acc[1][f] = __builtin_amdgcn_mfma_f32_16x16x32_f16(a1, b, acc[1][f], 0, 0, 0);
        }
    }
    #pragma unroll
    for (int f = 0; f < 8; ++f) {
        float bv = bias[cb + f * 16 + coll];
        #pragma unroll
        for (int r = 0; r < 2; ++r)
            #pragma unroll
            for (int g = 0; g < 4; ++g) {
                int m = mbase + r * 16 + (lane >> 4) * 4 + g;
                float v = acc[r][f][g] + bv;
                v = v > 0.f ? v : 0.f;
                Y[(size_t)m * HID + cb + f * 16 + coll] = __float2half(v);
            }
    }
}

// ---------------- conv_transpose: ALL 4 parities per wave --------------------
// For shift (du,dv) in {-1,0,1}^2, A is loaded ONCE and feeds every
// (parity, tap) combo with t1-1+pi == du, t2-1+pj == dv (16 combos, 9 loads).
// CF = #16-wide output-channel fragments per block; blockIdx.y selects slice.
template <int CIN, int COUT, int HIN, int R, int LOGH, int CF, int OH, int OB>
__global__ __launch_bounds__(256) void convt_mfma2(
    const __half* __restrict__ X, const __half* __restrict__ Bt,
    const float* __restrict__ bias, __half* __restrict__ Y) {
    constexpr int HH = HIN * HIN;
    constexpr int KTOT = 4 * CIN;
    constexpr int NSTEP = CIN / 32;
    int lane = threadIdx.x & 63, wid = threadIdx.x >> 6;
    int job = blockIdx.x * 4 + wid;
    int posbase = job * (R * 16);
    int cbase = blockIdx.y * (CF * 16);
    int klane = (lane >> 4) * 8, coll = lane & 15;

    long ibase[R];
    bool rv[R][3], cv[R][3];
    #pragma unroll
    for (int r = 0; r < R; ++r) {
        int p = posbase + r * 16 + coll;
        int n = p >> (2 * LOGH);
        int rem = p & (HH - 1);
        int a = rem >> LOGH, b = rem & (HIN - 1);
        ibase[r] = ((long)n * HH + a * HIN + b) * CIN + klane;
        #pragma unroll
        for (int s = 0; s < 3; ++s) {
            rv[r][s] = (unsigned)(a + s - 1) < (unsigned)HIN;
            cv[r][s] = (unsigned)(b + s - 1) < (unsigned)HIN;
        }
    }

    f32x4 acc[4][R][CF] = {};

    #pragma unroll
    for (int iu = 0; iu < 3; ++iu) {
        #pragma unroll
        for (int iv = 0; iv < 3; ++iv) {
            const long soff = ((iu - 1) * HIN + (iv - 1)) * CIN;
            #pragma unroll
            for (int cc = 0; cc < NSTEP; ++cc) {
                f16x8 a[R];
                #pragma unroll
                for (int r = 0; r < R; ++r) {
                    f16x8 v = {0, 0, 0, 0, 0, 0, 0, 0};
                    if (rv[r][iu] && cv[r][iv])
                        v = *(const f16x8*)(X + ibase[r] + soff + cc * 32);
                    a[r] = v;
                }
                #pragma unroll
                for (int pi = 0; pi < 2; ++pi) {
                    if (pi > iu || pi + 1 < iu) continue;     // t1 = iu-pi in {0,1}
                    #pragma unroll
                    for (int pj = 0; pj < 2; ++pj) {
                        if (pj > iv || pj + 1 < iv) continue; // t2 = iv-pj in {0,1}
                        int par = pi + 2 * pj;
                        int tap = (iu - pi) * 2 + (iv - pj);
                        f16x8 bfr[CF];
                        #pragma unroll
                        for (int f = 0; f < CF; ++f)
                            bfr[f] = *(const f16x8*)(Bt +
                                (size_t)(par * COUT + cbase + f * 16 + coll) * KTOT +
                                tap * CIN + cc * 32 + klane);
                        #pragma unroll
                        for (int r = 0; r < R; ++r)
                            #pragma unroll
                            for (int f = 0; f < CF; ++f)
                                acc[par][r][f] = __builtin_amdgcn_mfma_f32_16x16x32_f16(
                                    a[r], bfr[f], acc[par][r][f], 0, 0, 0);
                    }
                }
            }
        }
    }

    float bv[CF];
    #pragma unroll
    for (int f = 0; f < CF; ++f) bv[f] = bias[cbase + f * 16 + coll];

    #pragma unroll
    for (int par = 0; par < 4; ++par) {
        int pi = par & 1, pj = par >> 1;
        #pragma unroll
        for (int r = 0; r < R; ++r) {
            #pragma unroll
            for (int g = 0; g < 4; ++g) {
                int p = posbase + r * 16 + (lane >> 4) * 4 + g;
                int n = p >> (2 * LOGH);
                int rem = p & (HH - 1);
                int a2 = rem >> LOGH, b2 = rem & (HIN - 1);
                size_t ob = (((size_t)n * OH + 2 * a2 + pi + OB) * OH + 2 * b2 + pj + OB) * COUT;
                #pragma unroll
                for (int f = 0; f < CF; ++f) {
                    float v = acc[par][r][f][g] + bv[f];
                    v = v > 0.f ? v : 0.f;
                    Y[ob + cbase + f * 16 + coll] = __float2half(v);
                }
            }
        }
    }
}

// ---------------- zero the 1-wide border ring of padded x3 -------------------
__global__ __launch_bounds__(256) void pad_zero(__half* __restrict__ Xp) {
    int n = blockIdx.x;
    __half* base = Xp + (size_t)n * 34 * 34 * 32;
    for (int w = threadIdx.x; w < 132 * 4; w += 256) {
        int posi = w >> 2, q = w & 3;
        int r, s;
        if (posi < 68) { r = (posi < 34) ? 0 : 33; s = posi % 34; }
        else { int e = posi - 68; r = 1 + (e >> 1); s = (e & 1) ? 33 : 0; }
        *(f16x8*)(base + ((size_t)r * 34 + s) * 32 + q * 8) = (f16x8){0, 0, 0, 0, 0, 0, 0, 0};
    }
}

// ---------------- conv4: padded 34x34x32 -> 64x64x1, fp32 out ----------------
__global__ __launch_bounds__(256) void conv4_kernel2(
    const __half* __restrict__ Xp, const __half* __restrict__ Wh,
    const float* __restrict__ bias, float* __restrict__ out) {
    int n = blockIdx.x;
    int t = threadIdx.x;
    int b = t & 31;
    int a = (blockIdx.y << 3) + (t >> 5);
    const __half* Xn = Xp + (size_t)n * 34 * 34 * 32;
    const f16x2* W2 = (const f16x2*)Wh;
    float a00 = 0.f, a01 = 0.f, a10 = 0.f, a11 = 0.f;
    #pragma unroll
    for (int hf = 0; hf < 2; ++hf) {
        f16x2 xw[9][8];
        #pragma unroll
        for (int u = 0; u < 3; ++u)
            #pragma unroll
            for (int v = 0; v < 3; ++v) {
                const f16x8* p = (const f16x8*)(Xn + ((size_t)(a + u) * 34 + (b + v)) * 32 + hf * 16);
                f16x8 lo = p[0], hi = p[1];
                #pragma unroll
                for (int e = 0; e < 4; ++e) {
                    xw[u * 3 + v][e]     = (f16x2){lo[2 * e], lo[2 * e + 1]};
                    xw[u * 3 + v][e + 4] = (f16x2){hi[2 * e], hi[2 * e + 1]};
                }
            }
        #pragma unroll
        for (int pi = 0; pi < 2; ++pi)
            #pragma unroll
            for (int pj = 0; pj < 2; ++pj) {
                float acc = pi ? (pj ? a11 : a10) : (pj ? a01 : a00);
                #pragma unroll
                for (int t1 = 0; t1 < 2; ++t1)
                    #pragma unroll
                    for (int t2 = 0; t2 < 2; ++t2) {
                        int pos = (pi + t1) * 3 + (pj + t2);
                        const f16x2* wrow = W2 + ((pi + 2 * t1) * 4 + (pj + 2 * t2)) * 16 + hf * 8;
                        #pragma unroll
                        for (int e = 0; e < 8; ++e)
                            acc = dot2f(xw[pos][e], wrow[e], acc);
                    }
                if (pi) { if (pj) a11 = acc; else a10 = acc; }
                else    { if (pj) a01 = acc; else a00 = acc; }
            }
    }
    float bv = bias[0];
    out[((size_t)n * 64 + 2 * a + 0) * 64 + 2 * b + 0] = a00 + bv;
    out[((size_t)n * 64 + 2 * a + 0) * 64 + 2 * b + 1] = a01 + bv;
    out[((size_t)n * 64 + 2 * a + 1) * 64 + 2 * b + 0] = a10 + bv;
    out[((size_t)n * 64 + 2 * a + 1) * 64 + 2 * b + 1] = a11 + bv;
}

// ---------------- launch -----------------------------------------------------
extern "C" void kernel_launch(void* const* d_in, const int* in_sizes, int n_in,
                              void* d_out, int out_size, void* d_ws, size_t ws_size,
                              hipStream_t stream) {
    const float* angles   = (const float*)d_in[0];
    const float* item_rep = (const float*)d_in[1];
    const float* W        = (const float*)d_in[2];
    const float* bfc      = (const float*)d_in[3];
    const float* k1       = (const float*)d_in[4];
    const float* b1       = (const float*)d_in[5];
    const float* k2       = (const float*)d_in[6];
    const float* b2       = (const float*)d_in[7];
    const float* k3       = (const float*)d_in[8];
    const float* b3       = (const float*)d_in[9];
    const float* k4       = (const float*)d_in[10];
    const float* b4       = (const float*)d_in[11];

    char* ws = (char*)d_ws;
    // ws layout (max offset 222,822,400):
    //   x3p (padded 2048x34x34x32 f16, 151.5 MB) aliases dead x0+x1+Wtfc;
    //   write order: fc->x0, conv1->x1, conv2->x2, pad_zero+conv3->x3p, conv4.
    float*  Ctab  = (float*)(ws + 0);                 //  32 KB
    __half* itemh = (__half*)(ws + 32768);            //   2 MB
    __half* Bt1   = (__half*)(ws + 2129920);          //   1 MB
    __half* Bt2   = (__half*)(ws + 3178496);          // 256 KB
    __half* Bt3   = (__half*)(ws + 3440640);          //  64 KB
    __half* Kh4   = (__half*)(ws + 3506176);          //   1 KB
    __half* x0    = (__half*)(ws + 4194304);          //  16 MB -> 20,971,520
    __half* x1    = (__half*)(ws + 20971520);         //  32 MB -> 54,525,952
    __half* x3p   = (__half*)(ws + 4194304);          // 151.5 MB -> 155,713,536
    __half* Wtfc  = (__half*)(ws + 121634816);        //   4 MB (inside x3p, dead by conv3)
    __half* x2    = (__half*)(ws + 155713536);        //  64 MB -> 222,822,400
    float*  out   = (float*)d_out;

    coef_kernel<<<1, 512, 0, stream>>>(Ctab);
    wigner_kernel<<<NBATCH, 64, 0, stream>>>(angles, item_rep, Ctab, itemh);
    fcw_prep<<<HID / 256, 256, 0, stream>>>(W, Wtfc);
    convw_prep<256, 128><<<16, 256, 0, stream>>>(k1, Bt1);
    convw_prep<128, 64><<<16, 256, 0, stream>>>(k2, Bt2);
    convw_prep<64, 32><<<16, 256, 0, stream>>>(k3, Bt3);
    conv4w_prep<<<2, 256, 0, stream>>>(k4, Kh4);

    // FC: 2048x512 @ 512x4096 -> x0
    fc_mfma<<<dim3(16, 32), 256, 0, stream>>>(itemh, Wtfc, bfc, x0);
    // conv1: 4x4x256 -> 8x8x128   (R=2, CF=4, 2 channel slices)
    convt_mfma2<256, 128, 4, 2, 2, 4, 8, 0><<<dim3(256, 2), 256, 0, stream>>>(x0, Bt1, b1, x1);
    // conv2: 8x8x128 -> 16x16x64  (R=2, CF=4)
    convt_mfma2<128, 64, 8, 2, 3, 4, 16, 0><<<dim3(1024, 1), 256, 0, stream>>>(x1, Bt2, b2, x2);
    // zero x3p border ring, then conv3 writes the 32x32 interior at +1
    pad_zero<<<NBATCH, 256, 0, stream>>>(x3p);
    // conv3: 16x16x64 -> (34x34 padded)x32 (R=4, CF=2)
    convt_mfma2<64, 32, 16, 4, 4, 2, 34, 1><<<dim3(2048, 1), 256, 0, stream>>>(x2, Bt3, b3, x3p);
    // conv4: padded 34x34x32 -> 64x64x1 (fp32 out)
    conv4_kernel2<<<dim3(NBATCH, 4), 256, 0, stream>>>(x3p, Kh4, b4, out);
}

// Round 5
// 634.549 us; speedup vs baseline: 12.4383x; 1.2472x over previous
//
#include <hip/hip_runtime.h>
#include <hip/hip_fp16.h>

#define DEG 6
#define RC 10
#define NBATCH 2048
#define FDIM 490
#define KPAD 512
#define HID 4096

typedef _Float16 f16x8 __attribute__((ext_vector_type(8)));
typedef _Float16 f16x2 __attribute__((ext_vector_type(2)));
typedef float f32x4 __attribute__((ext_vector_type(4)));

__device__ inline float dot2f(f16x2 x, f16x2 w, float acc) {
#if __has_builtin(__builtin_amdgcn_fdot2)
    return __builtin_amdgcn_fdot2(x, w, acc, false);
#else
    return acc + (float)x[0] * (float)w[0] + (float)x[1] * (float)w[1];
#endif
}

// ---------------- Wigner coefficient tables (device, each call) --------------
__global__ void coef_kernel(float* __restrict__ Ctab) {
    int p = blockIdx.x * blockDim.x + threadIdx.x;
    if (p >= 455) return;
    const int poff[8] = {0, 1, 10, 35, 84, 165, 286, 455};
    const int loff[7] = {0, 1, 28, 153, 496, 1225, 2556};
    int l = 0;
    while (p >= poff[l + 1]) ++l;
    int idx = p - poff[l];
    int nn = 2 * l + 1;
    int mpi = idx / nn, mi = idx % nn;
    int mp = mpi - l, m = mi - l;
    double f[13];
    f[0] = 1.0;
    for (int i = 1; i < 13; ++i) f[i] = f[i - 1] * i;
    double pref = sqrt(f[l + mp] * f[l - mp] * f[l + m] * f[l - m]);
    float* row = Ctab + loff[l] + (size_t)(mpi * nn + mi) * nn;
    for (int q = 0; q < nn; ++q) row[q] = 0.f;
    int s0 = max(0, m - mp), s1 = min(l + m, l - mp);
    for (int s = s0; s <= s1; ++s) {
        int q = mp - m + 2 * s;
        double den = f[l + m - s] * f[s] * f[mp - m + s] * f[l - mp - s];
        double t = pref / den;
        if ((mp - m + s) & 1) t = -t;
        row[q] += (float)t;
    }
}

// ---------------- Wigner D + item projection -> fp16 item[n][512] ------------
__global__ __launch_bounds__(64) void wigner_kernel(
    const float* __restrict__ angles, const float* __restrict__ item_rep,
    const float* __restrict__ Ctab, __half* __restrict__ item_h) {
    int n = blockIdx.x, lane = threadIdx.x;
    float alpha = angles[n * 3 + 0], beta = angles[n * 3 + 1], gamma = angles[n * 3 + 2];
    float cb = cosf(beta * 0.5f), sb = sinf(beta * 0.5f);
    __shared__ float dsh[169], Dsh[169], Psh[13];
    __shared__ float ear[13], eai[13], egr[13], egi[13];
    const int loff[7] = {0, 1, 28, 153, 496, 1225, 2556};
    const float isq = 0.7071067811865476f;
    for (int l = 0; l <= DEG; ++l) {
        int nn = 2 * l + 1;
        if (lane < nn) {
            int q = lane;
            float pv = 1.f;
            for (int i = 0; i < 2 * l - q; ++i) pv *= cb;
            for (int i = 0; i < q; ++i) pv *= sb;
            Psh[q] = pv;
            float mm = (float)(lane - l);
            float sa, ca; sincosf(alpha * mm, &sa, &ca);
            ear[lane] = ca; eai[lane] = -sa;
            float sg, cg; sincosf(gamma * mm, &sg, &cg);
            egr[lane] = cg; egi[lane] = -sg;
        }
        __syncthreads();
        const float* Cl = Ctab + loff[l];
        for (int e = lane; e < nn * nn; e += 64) {
            float acc = 0.f;
            const float* cr = Cl + e * nn;
            for (int q = 0; q < nn; ++q) acc += cr[q] * Psh[q];
            dsh[e] = acc;
        }
        __syncthreads();
        for (int e = lane; e < nn * nn; e += 64) {
            int u = e / nn, v = e - u * nn;
            int bn, bi0, bi1; float br0, br1, bm0, bm1;
            int mu = u - l;
            if (mu == 0)      { bn = 1; bi0 = l; br0 = 1.f; bm0 = 0.f; bi1 = 0; br1 = 0.f; bm1 = 0.f; }
            else if (mu > 0)  { bn = 2; bi0 = l + mu; br0 = (mu & 1) ? -isq : isq; bm0 = 0.f;
                                bi1 = l - mu; br1 = isq; bm1 = 0.f; }
            else              { int mm2 = -mu; bn = 2; bi0 = l - mm2; br0 = 0.f; bm0 = isq;
                                bi1 = l + mm2; br1 = 0.f; bm1 = (mm2 & 1) ? isq : -isq; }
            int cn, ci0, ci1; float cr0, cr1, cm0, cm1;
            int nu = v - l;
            if (nu == 0)      { cn = 1; ci0 = l; cr0 = 1.f; cm0 = 0.f; ci1 = 0; cr1 = 0.f; cm1 = 0.f; }
            else if (nu > 0)  { cn = 2; ci0 = l + nu; cr0 = (nu & 1) ? -isq : isq; cm0 = 0.f;
                                ci1 = l - nu; cr1 = isq; cm1 = 0.f; }
            else              { int mm2 = -nu; cn = 2; ci0 = l - mm2; cr0 = 0.f; cm0 = -isq;
                                ci1 = l + mm2; cr1 = 0.f; cm1 = (mm2 & 1) ? -isq : isq; }
            float acc = 0.f;
            #pragma unroll
            for (int pb = 0; pb < 2; ++pb) {
                if (pb >= bn) break;
                int b = pb ? bi1 : bi0;
                float sr = pb ? br1 : br0, si = pb ? bm1 : bm0;
                float z1r = sr * ear[b] - si * eai[b];
                float z1i = sr * eai[b] + si * ear[b];
                #pragma unroll
                for (int pc = 0; pc < 2; ++pc) {
                    if (pc >= cn) break;
                    int c = pc ? ci1 : ci0;
                    float tr = pc ? cr1 : cr0, ti = pc ? cm1 : cm0;
                    float dv = dsh[b * nn + c];
                    float z2r = egr[c] * tr - egi[c] * ti;
                    float z2i = egr[c] * ti + egi[c] * tr;
                    acc += dv * (z1r * z2r - z1i * z2i);
                }
            }
            Dsh[e] = acc;
        }
        __syncthreads();
        for (int e = lane; e < nn * RC; e += 64) {
            int u = e / RC, r = e - u * RC;
            float acc = 0.f;
            for (int v = 0; v < nn; ++v)
                acc += Dsh[u * nn + v] * item_rep[(l * l + v) * RC + r];
            item_h[(size_t)n * KPAD + (l * l + u) * RC + r] = __float2half(acc);
        }
        __syncthreads();
    }
    if (lane < KPAD - FDIM)
        item_h[(size_t)n * KPAD + FDIM + lane] = __float2half(0.f);
}

// ------- FC weight prep (tiled transpose): W[490,4096] f32 -> Wt[4096][512] f16
// 64x64 tiles, coalesced loads, LDS-staged transpose, 16B f16x8 stores.
__global__ __launch_bounds__(256) void fcw_prep2(const float* __restrict__ W,
                                                 __half* __restrict__ Wt) {
    __shared__ _Float16 tile[64][72];   // +8 pad breaks transposed-read conflicts
    int k0 = blockIdx.x * 64;           // 8 tiles cover KPAD=512
    int o0 = blockIdx.y * 64;           // 64 tiles cover HID=4096
    int tid = threadIdx.x;
    int tx = tid & 63, ty = tid >> 6;
    #pragma unroll
    for (int i = 0; i < 16; ++i) {
        int k = k0 + ty + i * 4;
        float v = (k < FDIM) ? W[(size_t)k * HID + o0 + tx] : 0.f;
        tile[ty + i * 4][tx] = (_Float16)v;
    }
    __syncthreads();
    #pragma unroll
    for (int p = 0; p < 2; ++p) {
        int idx = tid + p * 256;
        int ol = idx >> 3;
        int kl = (idx & 7) * 8;
        f16x8 v;
        #pragma unroll
        for (int e = 0; e < 8; ++e) v[e] = tile[kl + e][ol];
        *(f16x8*)(Wt + (size_t)(o0 + ol) * KPAD + k0 + kl) = v;
    }
}

// ---- conv weight prep: K[4][4][CIN][COUT] f32 -> Bt[par][COUT][4*CIN] f16 ---
template <int CIN, int COUT>
__global__ __launch_bounds__(256) void convw_prep(const float* __restrict__ K,
                                                  __half* __restrict__ Bt) {
    int par = blockIdx.x >> 2, tap = blockIdx.x & 3;
    int pi = par & 1, pj = par >> 1;
    int t1 = tap >> 1, t2 = tap & 1;
    int dh = pi + 2 * t1, dw = pj + 2 * t2;
    const float* Ks = K + (size_t)(dh * 4 + dw) * CIN * COUT;
    int o = threadIdx.x % COUT;
    int cg = threadIdx.x / COUT;
    constexpr int NG = 256 / COUT;
    for (int c0 = cg * 8; c0 < CIN; c0 += NG * 8) {
        f16x8 v;
        #pragma unroll
        for (int e = 0; e < 8; ++e) v[e] = (_Float16)Ks[(size_t)(c0 + e) * COUT + o];
        *(f16x8*)(Bt + ((size_t)par * COUT + o) * (4 * CIN) + tap * CIN + c0) = v;
    }
}

// ---- conv4 weight prep: K[4][4][32][1] f32 -> f16 [16][32] ------------------
__global__ __launch_bounds__(256) void conv4w_prep(const float* __restrict__ K,
                                                   __half* __restrict__ Kh) {
    int t = blockIdx.x * blockDim.x + threadIdx.x;
    if (t < 512) Kh[t] = __float2half(K[t]);
}

// ---------------- FC as MFMA GEMM: [2048x512] x [512x4096] + relu -> f16 -----
__global__ __launch_bounds__(256) void fc_mfma(
    const __half* __restrict__ A, const __half* __restrict__ Wt,
    const float* __restrict__ bias, __half* __restrict__ Y) {
    int lane = threadIdx.x & 63, wid = threadIdx.x >> 6;
    int job = blockIdx.x * 4 + wid;
    int mbase = job * 32;
    int cb = blockIdx.y * 128;
    int klane = (lane >> 4) * 8, coll = lane & 15;
    const __half* pA0 = A + (size_t)(mbase + coll) * KPAD + klane;
    const __half* pB0 = Wt + (size_t)(cb + coll) * KPAD + klane;
    f32x4 acc[2][8] = {};
    for (int s = 0; s < 16; ++s) {
        f16x8 a0 = *(const f16x8*)(pA0 + s * 32);
        f16x8 a1 = *(const f16x8*)(pA0 + 16 * KPAD + s * 32);
        #pragma unroll
        for (int f = 0; f < 8; ++f) {
            f16x8 b = *(const f16x8*)(pB0 + (size_t)f * 16 * KPAD + s * 32);
            acc[0][f] = __builtin_amdgcn_mfma_f32_16x16x32_f16(a0, b, acc[0][f], 0, 0, 0);
            acc[1][f] = __builtin_amdgcn_mfma_f32_16x16x32_f16(a1, b, acc[1][f], 0, 0, 0);
        }
    }
    #pragma unroll
    for (int f = 0; f < 8; ++f) {
        float bv = bias[cb + f * 16 + coll];
        #pragma unroll
        for (int r = 0; r < 2; ++r)
            #pragma unroll
            for (int g = 0; g < 4; ++g) {
                int m = mbase + r * 16 + (lane >> 4) * 4 + g;
                float v = acc[r][f][g] + bv;
                v = v > 0.f ? v : 0.f;
                Y[(size_t)m * HID + cb + f * 16 + coll] = __float2half(v);
            }
    }
}

// ---------------- conv_transpose: ALL 4 parities per wave --------------------
// For shift (du,dv) in {-1,0,1}^2, A is loaded ONCE and feeds every
// (parity, tap) combo with t1-1+pi == du, t2-1+pj == dv (16 combos, 9 loads).
template <int CIN, int COUT, int HIN, int R, int LOGH, int CF, int OH, int OB>
__global__ __launch_bounds__(256) void convt_mfma2(
    const __half* __restrict__ X, const __half* __restrict__ Bt,
    const float* __restrict__ bias, __half* __restrict__ Y) {
    constexpr int HH = HIN * HIN;
    constexpr int KTOT = 4 * CIN;
    constexpr int NSTEP = CIN / 32;
    int lane = threadIdx.x & 63, wid = threadIdx.x >> 6;
    int job = blockIdx.x * 4 + wid;
    int posbase = job * (R * 16);
    int cbase = blockIdx.y * (CF * 16);
    int klane = (lane >> 4) * 8, coll = lane & 15;

    long ibase[R];
    bool rv[R][3], cv[R][3];
    #pragma unroll
    for (int r = 0; r < R; ++r) {
        int p = posbase + r * 16 + coll;
        int n = p >> (2 * LOGH);
        int rem = p & (HH - 1);
        int a = rem >> LOGH, b = rem & (HIN - 1);
        ibase[r] = ((long)n * HH + a * HIN + b) * CIN + klane;
        #pragma unroll
        for (int s = 0; s < 3; ++s) {
            rv[r][s] = (unsigned)(a + s - 1) < (unsigned)HIN;
            cv[r][s] = (unsigned)(b + s - 1) < (unsigned)HIN;
        }
    }

    f32x4 acc[4][R][CF] = {};

    #pragma unroll
    for (int iu = 0; iu < 3; ++iu) {
        #pragma unroll
        for (int iv = 0; iv < 3; ++iv) {
            const long soff = ((iu - 1) * HIN + (iv - 1)) * CIN;
            #pragma unroll
            for (int cc = 0; cc < NSTEP; ++cc) {
                f16x8 a[R];
                #pragma unroll
                for (int r = 0; r < R; ++r) {
                    f16x8 v = {0, 0, 0, 0, 0, 0, 0, 0};
                    if (rv[r][iu] && cv[r][iv])
                        v = *(const f16x8*)(X + ibase[r] + soff + cc * 32);
                    a[r] = v;
                }
                #pragma unroll
                for (int pi = 0; pi < 2; ++pi) {
                    if (pi > iu || pi + 1 < iu) continue;     // t1 = iu-pi in {0,1}
                    #pragma unroll
                    for (int pj = 0; pj < 2; ++pj) {
                        if (pj > iv || pj + 1 < iv) continue; // t2 = iv-pj in {0,1}
                        int par = pi + 2 * pj;
                        int tap = (iu - pi) * 2 + (iv - pj);
                        f16x8 bfr[CF];
                        #pragma unroll
                        for (int f = 0; f < CF; ++f)
                            bfr[f] = *(const f16x8*)(Bt +
                                (size_t)(par * COUT + cbase + f * 16 + coll) * KTOT +
                                tap * CIN + cc * 32 + klane);
                        #pragma unroll
                        for (int r = 0; r < R; ++r)
                            #pragma unroll
                            for (int f = 0; f < CF; ++f)
                                acc[par][r][f] = __builtin_amdgcn_mfma_f32_16x16x32_f16(
                                    a[r], bfr[f], acc[par][r][f], 0, 0, 0);
                    }
                }
            }
        }
    }

    float bv[CF];
    #pragma unroll
    for (int f = 0; f < CF; ++f) bv[f] = bias[cbase + f * 16 + coll];

    #pragma unroll
    for (int par = 0; par < 4; ++par) {
        int pi = par & 1, pj = par >> 1;
        #pragma unroll
        for (int r = 0; r < R; ++r) {
            #pragma unroll
            for (int g = 0; g < 4; ++g) {
                int p = posbase + r * 16 + (lane >> 4) * 4 + g;
                int n = p >> (2 * LOGH);
                int rem = p & (HH - 1);
                int a2 = rem >> LOGH, b2 = rem & (HIN - 1);
                size_t ob = (((size_t)n * OH + 2 * a2 + pi + OB) * OH + 2 * b2 + pj + OB) * COUT;
                #pragma unroll
                for (int f = 0; f < CF; ++f) {
                    float v = acc[par][r][f][g] + bv[f];
                    v = v > 0.f ? v : 0.f;
                    Y[ob + cbase + f * 16 + coll] = __float2half(v);
                }
            }
        }
    }
}

// ---------------- zero the 1-wide border ring of padded x3 -------------------
__global__ __launch_bounds__(256) void pad_zero(__half* __restrict__ Xp) {
    int n = blockIdx.x;
    __half* base = Xp + (size_t)n * 34 * 34 * 32;
    for (int w = threadIdx.x; w < 132 * 4; w += 256) {
        int posi = w >> 2, q = w & 3;
        int r, s;
        if (posi < 68) { r = (posi < 34) ? 0 : 33; s = posi % 34; }
        else { int e = posi - 68; r = 1 + (e >> 1); s = (e & 1) ? 33 : 0; }
        *(f16x8*)(base + ((size_t)r * 34 + s) * 32 + q * 8) = (f16x8){0, 0, 0, 0, 0, 0, 0, 0};
    }
}

// ---------------- conv4: padded 34x34x32 -> 64x64x1, fp32 out ----------------
__global__ __launch_bounds__(256) void conv4_kernel2(
    const __half* __restrict__ Xp, const __half* __restrict__ Wh,
    const float* __restrict__ bias, float* __restrict__ out) {
    int n = blockIdx.x;
    int t = threadIdx.x;
    int b = t & 31;
    int a = (blockIdx.y << 3) + (t >> 5);
    const __half* Xn = Xp + (size_t)n * 34 * 34 * 32;
    const f16x2* W2 = (const f16x2*)Wh;
    float a00 = 0.f, a01 = 0.f, a10 = 0.f, a11 = 0.f;
    #pragma unroll
    for (int hf = 0; hf < 2; ++hf) {
        f16x2 xw[9][8];
        #pragma unroll
        for (int u = 0; u < 3; ++u)
            #pragma unroll
            for (int v = 0; v < 3; ++v) {
                const f16x8* p = (const f16x8*)(Xn + ((size_t)(a + u) * 34 + (b + v)) * 32 + hf * 16);
                f16x8 lo = p[0], hi = p[1];
                #pragma unroll
                for (int e = 0; e < 4; ++e) {
                    xw[u * 3 + v][e]     = (f16x2){lo[2 * e], lo[2 * e + 1]};
                    xw[u * 3 + v][e + 4] = (f16x2){hi[2 * e], hi[2 * e + 1]};
                }
            }
        #pragma unroll
        for (int pi = 0; pi < 2; ++pi)
            #pragma unroll
            for (int pj = 0; pj < 2; ++pj) {
                float acc = pi ? (pj ? a11 : a10) : (pj ? a01 : a00);
                #pragma unroll
                for (int t1 = 0; t1 < 2; ++t1)
                    #pragma unroll
                    for (int t2 = 0; t2 < 2; ++t2) {
                        int pos = (pi + t1) * 3 + (pj + t2);
                        const f16x2* wrow = W2 + ((pi + 2 * t1) * 4 + (pj + 2 * t2)) * 16 + hf * 8;
                        #pragma unroll
                        for (int e = 0; e < 8; ++e)
                            acc = dot2f(xw[pos][e], wrow[e], acc);
                    }
                if (pi) { if (pj) a11 = acc; else a10 = acc; }
                else    { if (pj) a01 = acc; else a00 = acc; }
            }
    }
    float bv = bias[0];
    out[((size_t)n * 64 + 2 * a + 0) * 64 + 2 * b + 0] = a00 + bv;
    out[((size_t)n * 64 + 2 * a + 0) * 64 + 2 * b + 1] = a01 + bv;
    out[((size_t)n * 64 + 2 * a + 1) * 64 + 2 * b + 0] = a10 + bv;
    out[((size_t)n * 64 + 2 * a + 1) * 64 + 2 * b + 1] = a11 + bv;
}

// ---------------- launch -----------------------------------------------------
extern "C" void kernel_launch(void* const* d_in, const int* in_sizes, int n_in,
                              void* d_out, int out_size, void* d_ws, size_t ws_size,
                              hipStream_t stream) {
    const float* angles   = (const float*)d_in[0];
    const float* item_rep = (const float*)d_in[1];
    const float* W        = (const float*)d_in[2];
    const float* bfc      = (const float*)d_in[3];
    const float* k1       = (const float*)d_in[4];
    const float* b1       = (const float*)d_in[5];
    const float* k2       = (const float*)d_in[6];
    const float* b2       = (const float*)d_in[7];
    const float* k3       = (const float*)d_in[8];
    const float* b3       = (const float*)d_in[9];
    const float* k4       = (const float*)d_in[10];
    const float* b4       = (const float*)d_in[11];

    char* ws = (char*)d_ws;
    // ws layout (max offset 222,822,400):
    //   x3p (padded 2048x34x34x32 f16, 151.5 MB) aliases dead x0+x1+Wtfc;
    //   write order: fc->x0, conv1->x1, conv2->x2, pad_zero+conv3->x3p, conv4.
    float*  Ctab  = (float*)(ws + 0);                 //  32 KB
    __half* itemh = (__half*)(ws + 32768);            //   2 MB
    __half* Bt1   = (__half*)(ws + 2129920);          //   1 MB
    __half* Bt2   = (__half*)(ws + 3178496);          // 256 KB
    __half* Bt3   = (__half*)(ws + 3440640);          //  64 KB
    __half* Kh4   = (__half*)(ws + 3506176);          //   1 KB
    __half* x0    = (__half*)(ws + 4194304);          //  16 MB -> 20,971,520
    __half* x1    = (__half*)(ws + 20971520);         //  32 MB -> 54,525,952
    __half* x3p   = (__half*)(ws + 4194304);          // 151.5 MB -> 155,713,536
    __half* Wtfc  = (__half*)(ws + 121634816);        //   4 MB (inside x3p, dead by conv3)
    __half* x2    = (__half*)(ws + 155713536);        //  64 MB -> 222,822,400
    float*  out   = (float*)d_out;

    coef_kernel<<<1, 512, 0, stream>>>(Ctab);
    wigner_kernel<<<NBATCH, 64, 0, stream>>>(angles, item_rep, Ctab, itemh);
    fcw_prep2<<<dim3(KPAD / 64, HID / 64), 256, 0, stream>>>(W, Wtfc);
    convw_prep<256, 128><<<16, 256, 0, stream>>>(k1, Bt1);
    convw_prep<128, 64><<<16, 256, 0, stream>>>(k2, Bt2);
    convw_prep<64, 32><<<16, 256, 0, stream>>>(k3, Bt3);
    conv4w_prep<<<2, 256, 0, stream>>>(k4, Kh4);

    // FC: 2048x512 @ 512x4096 -> x0
    fc_mfma<<<dim3(16, 32), 256, 0, stream>>>(itemh, Wtfc, bfc, x0);
    // conv1: 4x4x256 -> 8x8x128   (R=2, CF=4, 2 channel slices)
    convt_mfma2<256, 128, 4, 2, 2, 4, 8, 0><<<dim3(256, 2), 256, 0, stream>>>(x0, Bt1, b1, x1);
    // conv2: 8x8x128 -> 16x16x64  (R=2, CF=4)
    convt_mfma2<128, 64, 8, 2, 3, 4, 16, 0><<<dim3(1024, 1), 256, 0, stream>>>(x1, Bt2, b2, x2);
    // zero x3p border ring, then conv3 writes the 32x32 interior at +1
    pad_zero<<<NBATCH, 256, 0, stream>>>(x3p);
    // conv3: 16x16x64 -> (34x34 padded)x32 (R=4, CF=2)
    convt_mfma2<64, 32, 16, 4, 4, 2, 34, 1><<<dim3(2048, 1), 256, 0, stream>>>(x2, Bt3, b3, x3p);
    // conv4: padded 34x34x32 -> 64x64x1 (fp32 out)
    conv4_kernel2<<<dim3(NBATCH, 4), 256, 0, stream>>>(x3p, Kh4, b4, out);
}

// Round 6
// 408.962 us; speedup vs baseline: 19.2993x; 1.5516x over previous
//
#include <hip/hip_runtime.h>
#include <hip/hip_fp16.h>

#define DEG 6
#define RC 10
#define NBATCH 2048
#define FDIM 490
#define KPAD 512
#define HID 4096

typedef _Float16 f16x8 __attribute__((ext_vector_type(8)));
typedef _Float16 f16x2 __attribute__((ext_vector_type(2)));
typedef float f32x4 __attribute__((ext_vector_type(4)));

__device__ inline float dot2f(f16x2 x, f16x2 w, float acc) {
#if __has_builtin(__builtin_amdgcn_fdot2)
    return __builtin_amdgcn_fdot2(x, w, acc, false);
#else
    return acc + (float)x[0] * (float)w[0] + (float)x[1] * (float)w[1];
#endif
}

// ---------------- Wigner coefficient tables (device, each call) --------------
__global__ void coef_kernel(float* __restrict__ Ctab) {
    int p = blockIdx.x * blockDim.x + threadIdx.x;
    if (p >= 455) return;
    const int poff[8] = {0, 1, 10, 35, 84, 165, 286, 455};
    const int loff[7] = {0, 1, 28, 153, 496, 1225, 2556};
    int l = 0;
    while (p >= poff[l + 1]) ++l;
    int idx = p - poff[l];
    int nn = 2 * l + 1;
    int mpi = idx / nn, mi = idx % nn;
    int mp = mpi - l, m = mi - l;
    double f[13];
    f[0] = 1.0;
    for (int i = 1; i < 13; ++i) f[i] = f[i - 1] * i;
    double pref = sqrt(f[l + mp] * f[l - mp] * f[l + m] * f[l - m]);
    float* row = Ctab + loff[l] + (size_t)(mpi * nn + mi) * nn;
    for (int q = 0; q < nn; ++q) row[q] = 0.f;
    int s0 = max(0, m - mp), s1 = min(l + m, l - mp);
    for (int s = s0; s <= s1; ++s) {
        int q = mp - m + 2 * s;
        double den = f[l + m - s] * f[s] * f[mp - m + s] * f[l - mp - s];
        double t = pref / den;
        if ((mp - m + s) & 1) t = -t;
        row[q] += (float)t;
    }
}

// ---------------- Wigner D + item projection -> fp16 item[n][512] ------------
__global__ __launch_bounds__(64) void wigner_kernel(
    const float* __restrict__ angles, const float* __restrict__ item_rep,
    const float* __restrict__ Ctab, __half* __restrict__ item_h) {
    int n = blockIdx.x, lane = threadIdx.x;
    float alpha = angles[n * 3 + 0], beta = angles[n * 3 + 1], gamma = angles[n * 3 + 2];
    float cb = cosf(beta * 0.5f), sb = sinf(beta * 0.5f);
    __shared__ float dsh[169], Dsh[169], Psh[13];
    __shared__ float ear[13], eai[13], egr[13], egi[13];
    const int loff[7] = {0, 1, 28, 153, 496, 1225, 2556};
    const float isq = 0.7071067811865476f;
    for (int l = 0; l <= DEG; ++l) {
        int nn = 2 * l + 1;
        if (lane < nn) {
            int q = lane;
            float pv = 1.f;
            for (int i = 0; i < 2 * l - q; ++i) pv *= cb;
            for (int i = 0; i < q; ++i) pv *= sb;
            Psh[q] = pv;
            float mm = (float)(lane - l);
            float sa, ca; sincosf(alpha * mm, &sa, &ca);
            ear[lane] = ca; eai[lane] = -sa;
            float sg, cg; sincosf(gamma * mm, &sg, &cg);
            egr[lane] = cg; egi[lane] = -sg;
        }
        __syncthreads();
        const float* Cl = Ctab + loff[l];
        for (int e = lane; e < nn * nn; e += 64) {
            float acc = 0.f;
            const float* cr = Cl + e * nn;
            for (int q = 0; q < nn; ++q) acc += cr[q] * Psh[q];
            dsh[e] = acc;
        }
        __syncthreads();
        for (int e = lane; e < nn * nn; e += 64) {
            int u = e / nn, v = e - u * nn;
            int bn, bi0, bi1; float br0, br1, bm0, bm1;
            int mu = u - l;
            if (mu == 0)      { bn = 1; bi0 = l; br0 = 1.f; bm0 = 0.f; bi1 = 0; br1 = 0.f; bm1 = 0.f; }
            else if (mu > 0)  { bn = 2; bi0 = l + mu; br0 = (mu & 1) ? -isq : isq; bm0 = 0.f;
                                bi1 = l - mu; br1 = isq; bm1 = 0.f; }
            else              { int mm2 = -mu; bn = 2; bi0 = l - mm2; br0 = 0.f; bm0 = isq;
                                bi1 = l + mm2; br1 = 0.f; bm1 = (mm2 & 1) ? isq : -isq; }
            int cn, ci0, ci1; float cr0, cr1, cm0, cm1;
            int nu = v - l;
            if (nu == 0)      { cn = 1; ci0 = l; cr0 = 1.f; cm0 = 0.f; ci1 = 0; cr1 = 0.f; cm1 = 0.f; }
            else if (nu > 0)  { cn = 2; ci0 = l + nu; cr0 = (nu & 1) ? -isq : isq; cm0 = 0.f;
                                ci1 = l - nu; cr1 = isq; cm1 = 0.f; }
            else              { int mm2 = -nu; cn = 2; ci0 = l - mm2; cr0 = 0.f; cm0 = -isq;
                                ci1 = l + mm2; cr1 = 0.f; cm1 = (mm2 & 1) ? -isq : isq; }
            float acc = 0.f;
            #pragma unroll
            for (int pb = 0; pb < 2; ++pb) {
                if (pb >= bn) break;
                int b = pb ? bi1 : bi0;
                float sr = pb ? br1 : br0, si = pb ? bm1 : bm0;
                float z1r = sr * ear[b] - si * eai[b];
                float z1i = sr * eai[b] + si * ear[b];
                #pragma unroll
                for (int pc = 0; pc < 2; ++pc) {
                    if (pc >= cn) break;
                    int c = pc ? ci1 : ci0;
                    float tr = pc ? cr1 : cr0, ti = pc ? cm1 : cm0;
                    float dv = dsh[b * nn + c];
                    float z2r = egr[c] * tr - egi[c] * ti;
                    float z2i = egr[c] * ti + egi[c] * tr;
                    acc += dv * (z1r * z2r - z1i * z2i);
                }
            }
            Dsh[e] = acc;
        }
        __syncthreads();
        for (int e = lane; e < nn * RC; e += 64) {
            int u = e / RC, r = e - u * RC;
            float acc = 0.f;
            for (int v = 0; v < nn; ++v)
                acc += Dsh[u * nn + v] * item_rep[(l * l + v) * RC + r];
            item_h[(size_t)n * KPAD + (l * l + u) * RC + r] = __float2half(acc);
        }
        __syncthreads();
    }
    if (lane < KPAD - FDIM)
        item_h[(size_t)n * KPAD + FDIM + lane] = __float2half(0.f);
}

// ------- FC weight prep (tiled transpose): W[490,4096] f32 -> Wt[4096][512] f16
__global__ __launch_bounds__(256) void fcw_prep2(const float* __restrict__ W,
                                                 __half* __restrict__ Wt) {
    __shared__ _Float16 tile[64][72];
    int k0 = blockIdx.x * 64;
    int o0 = blockIdx.y * 64;
    int tid = threadIdx.x;
    int tx = tid & 63, ty = tid >> 6;
    #pragma unroll
    for (int i = 0; i < 16; ++i) {
        int k = k0 + ty + i * 4;
        float v = (k < FDIM) ? W[(size_t)k * HID + o0 + tx] : 0.f;
        tile[ty + i * 4][tx] = (_Float16)v;
    }
    __syncthreads();
    #pragma unroll
    for (int p = 0; p < 2; ++p) {
        int idx = tid + p * 256;
        int ol = idx >> 3;
        int kl = (idx & 7) * 8;
        f16x8 v;
        #pragma unroll
        for (int e = 0; e < 8; ++e) v[e] = tile[kl + e][ol];
        *(f16x8*)(Wt + (size_t)(o0 + ol) * KPAD + k0 + kl) = v;
    }
}

// ---- conv weight prep: K[4][4][CIN][COUT] f32 -> Bt[par][COUT][4*CIN] f16 ---
template <int CIN, int COUT>
__global__ __launch_bounds__(256) void convw_prep(const float* __restrict__ K,
                                                  __half* __restrict__ Bt) {
    int par = blockIdx.x >> 2, tap = blockIdx.x & 3;
    int pi = par & 1, pj = par >> 1;
    int t1 = tap >> 1, t2 = tap & 1;
    int dh = pi + 2 * t1, dw = pj + 2 * t2;
    const float* Ks = K + (size_t)(dh * 4 + dw) * CIN * COUT;
    int o = threadIdx.x % COUT;
    int cg = threadIdx.x / COUT;
    constexpr int NG = 256 / COUT;
    for (int c0 = cg * 8; c0 < CIN; c0 += NG * 8) {
        f16x8 v;
        #pragma unroll
        for (int e = 0; e < 8; ++e) v[e] = (_Float16)Ks[(size_t)(c0 + e) * COUT + o];
        *(f16x8*)(Bt + ((size_t)par * COUT + o) * (4 * CIN) + tap * CIN + c0) = v;
    }
}

// ---- conv4 weight prep: K[4][4][32][1] f32 -> f16 [16][32] ------------------
__global__ __launch_bounds__(256) void conv4w_prep(const float* __restrict__ K,
                                                   __half* __restrict__ Kh) {
    int t = blockIdx.x * blockDim.x + threadIdx.x;
    if (t < 512) Kh[t] = __float2half(K[t]);
}

// ---------------- FC as MFMA GEMM: [2048x512] x [512x4096] + relu -> f16 -----
__global__ __launch_bounds__(256) void fc_mfma(
    const __half* __restrict__ A, const __half* __restrict__ Wt,
    const float* __restrict__ bias, __half* __restrict__ Y) {
    int lane = threadIdx.x & 63, wid = threadIdx.x >> 6;
    int job = blockIdx.x * 4 + wid;
    int mbase = job * 32;
    int cb = blockIdx.y * 128;
    int klane = (lane >> 4) * 8, coll = lane & 15;
    const __half* pA0 = A + (size_t)(mbase + coll) * KPAD + klane;
    const __half* pB0 = Wt + (size_t)(cb + coll) * KPAD + klane;
    f32x4 acc[2][8] = {};
    for (int s = 0; s < 16; ++s) {
        f16x8 a0 = *(const f16x8*)(pA0 + s * 32);
        f16x8 a1 = *(const f16x8*)(pA0 + 16 * KPAD + s * 32);
        #pragma unroll
        for (int f = 0; f < 8; ++f) {
            f16x8 b = *(const f16x8*)(pB0 + (size_t)f * 16 * KPAD + s * 32);
            acc[0][f] = __builtin_amdgcn_mfma_f32_16x16x32_f16(a0, b, acc[0][f], 0, 0, 0);
            acc[1][f] = __builtin_amdgcn_mfma_f32_16x16x32_f16(a1, b, acc[1][f], 0, 0, 0);
        }
    }
    #pragma unroll
    for (int f = 0; f < 8; ++f) {
        float bv = bias[cb + f * 16 + coll];
        #pragma unroll
        for (int r = 0; r < 2; ++r)
            #pragma unroll
            for (int g = 0; g < 4; ++g) {
                int m = mbase + r * 16 + (lane >> 4) * 4 + g;
                float v = acc[r][f][g] + bv;
                v = v > 0.f ? v : 0.f;
                Y[(size_t)m * HID + cb + f * 16 + coll] = __float2half(v);
            }
    }
}

// ---------------- conv_transpose: LDS-staged A + double-buffered B -----------
// Block stages whole image(s) in LDS (halo = zeros via validity masks), loops
// the 16 (par,tap) combos with B slice double-buffered (issue-early loads,
// write-late, one barrier per combo). All LDS rows XOR-swizzled: slot ^= row&7.
template <int CIN, int COUT, int HIN, int R, int LOGH, int CF, int WAVES, int OH, int OB>
__global__ __launch_bounds__(WAVES * 64) void convt_lds(
    const __half* __restrict__ X, const __half* __restrict__ Bt,
    const float* __restrict__ bias, __half* __restrict__ Y) {
    constexpr int HH = HIN * HIN;
    constexpr int KTOT = 4 * CIN;
    constexpr int NSTEP = CIN / 32;
    constexpr int SL = CIN / 8;                       // 16B slots per row
    constexpr int LSL = (CIN == 256) ? 5 : ((CIN == 128) ? 4 : 3);
    constexpr int T = WAVES * 64;
    constexpr int POS = WAVES * R * 16;               // positions per block
    constexpr int AROWS = POS;
    constexpr int AH = AROWS * CIN;                   // A halves
    constexpr int BH = CF * 16 * CIN;                 // B halves per buffer
    constexpr int SA = AROWS * SL;
    constexpr int SB = CF * 16 * SL;
    constexpr int NSB = (SB + T - 1) / T;
    __shared__ _Float16 lds[AH + 2 * BH];

    int tid = threadIdx.x;
    int lane = tid & 63, w = tid >> 6;
    int kg = lane >> 4, coll = lane & 15;
    int n0 = blockIdx.x * (POS >> (2 * LOGH));
    int cbase = blockIdx.y * (CF * 16);
    int wbase = w * (R * 16);

    // stage A (swizzled)
    const __half* Xs = X + (size_t)n0 * HH * CIN;
    for (int i = tid; i < SA; i += T) {
        int row = i >> LSL, slot = i & (SL - 1);
        f16x8 v = *(const f16x8*)(Xs + (size_t)i * 8);
        *(f16x8*)(&lds[row * CIN + ((slot ^ (row & 7)) * 8)]) = v;
    }
    // stage B combo 0 into buffer 0
    f16x8 breg[NSB];
    #pragma unroll
    for (int q = 0; q < NSB; ++q) {
        int i = tid + q * T;
        if (i < SB) {
            int o = i >> LSL, slot = i & (SL - 1);
            breg[q] = *(const f16x8*)(Bt + ((size_t)(cbase + o) * KTOT) + slot * 8);
        }
    }
    #pragma unroll
    for (int q = 0; q < NSB; ++q) {
        int i = tid + q * T;
        if (i < SB) {
            int o = i >> LSL, slot = i & (SL - 1);
            *(f16x8*)(&lds[AH + o * CIN + ((slot ^ (o & 7)) * 8)]) = breg[q];
        }
    }
    __syncthreads();

    int posl[R]; bool okr[R][3], okc[R][3];
    #pragma unroll
    for (int r = 0; r < R; ++r) {
        int p = wbase + r * 16 + coll;
        posl[r] = p;
        int rem = p & (HH - 1);
        int a = rem >> LOGH, b = rem & (HIN - 1);
        #pragma unroll
        for (int s = 0; s < 3; ++s) {
            okr[r][s] = (unsigned)(a + s - 1) < (unsigned)HIN;
            okc[r][s] = (unsigned)(b + s - 1) < (unsigned)HIN;
        }
    }

    f32x4 acc[4][R][CF] = {};

    #pragma unroll
    for (int c = 0; c < 16; ++c) {
        const int par = c >> 2, tap = c & 3;
        const int pi = par & 1, pj = par >> 1;
        const int iu = (tap >> 1) + pi, iv = (tap & 1) + pj;   // shift idx 0..2
        // issue next combo's B loads early
        if (c < 15) {
            const int par2 = (c + 1) >> 2, tap2 = (c + 1) & 3;
            #pragma unroll
            for (int q = 0; q < NSB; ++q) {
                int i = tid + q * T;
                if (i < SB) {
                    int o = i >> LSL, slot = i & (SL - 1);
                    breg[q] = *(const f16x8*)(Bt +
                        ((size_t)(par2 * COUT + cbase + o) * KTOT + tap2 * CIN) + slot * 8);
                }
            }
        }
        // compute combo c from buffer c&1
        const _Float16* Bl = &lds[AH + (c & 1) * BH];
        #pragma unroll
        for (int cc = 0; cc < NSTEP; ++cc) {
            int ks = cc * 4 + kg;
            f16x8 a[R];
            #pragma unroll
            for (int r = 0; r < R; ++r) {
                bool ok = okr[r][iu] && okc[r][iv];
                int rp = posl[r] + (iu - 1) * HIN + (iv - 1);
                rp = min(max(rp, 0), AROWS - 1);
                f16x8 v = *(const f16x8*)(&lds[rp * CIN + ((ks ^ (rp & 7)) * 8)]);
                a[r] = ok ? v : (f16x8){0, 0, 0, 0, 0, 0, 0, 0};
            }
            #pragma unroll
            for (int f = 0; f < CF; ++f) {
                int o = f * 16 + coll;
                f16x8 b = *(const f16x8*)(&Bl[o * CIN + ((ks ^ (o & 7)) * 8)]);
                #pragma unroll
                for (int r = 0; r < R; ++r)
                    acc[par][r][f] = __builtin_amdgcn_mfma_f32_16x16x32_f16(
                        a[r], b, acc[par][r][f], 0, 0, 0);
            }
        }
        // write-late + barrier
        if (c < 15) {
            #pragma unroll
            for (int q = 0; q < NSB; ++q) {
                int i = tid + q * T;
                if (i < SB) {
                    int o = i >> LSL, slot = i & (SL - 1);
                    *(f16x8*)(&lds[AH + ((c + 1) & 1) * BH + o * CIN +
                                   ((slot ^ (o & 7)) * 8)]) = breg[q];
                }
            }
            __syncthreads();
        }
    }

    float bv[CF];
    #pragma unroll
    for (int f = 0; f < CF; ++f) bv[f] = bias[cbase + f * 16 + coll];
    #pragma unroll
    for (int par = 0; par < 4; ++par) {
        int pi = par & 1, pj = par >> 1;
        #pragma unroll
        for (int r = 0; r < R; ++r) {
            #pragma unroll
            for (int g = 0; g < 4; ++g) {
                int p = wbase + r * 16 + kg * 4 + g;
                int ni = p >> (2 * LOGH);
                int rem = p & (HH - 1);
                int a2 = rem >> LOGH, b2 = rem & (HIN - 1);
                size_t ob = (((size_t)(n0 + ni) * OH + 2 * a2 + pi + OB) * OH +
                             2 * b2 + pj + OB) * COUT;
                #pragma unroll
                for (int f = 0; f < CF; ++f) {
                    float v = acc[par][r][f][g] + bv[f];
                    v = v > 0.f ? v : 0.f;
                    Y[ob + cbase + f * 16 + coll] = __float2half(v);
                }
            }
        }
    }
}

// ---------------- zero the 1-wide border ring of padded x3 -------------------
__global__ __launch_bounds__(256) void pad_zero(__half* __restrict__ Xp) {
    int n = blockIdx.x;
    __half* base = Xp + (size_t)n * 34 * 34 * 32;
    for (int w = threadIdx.x; w < 132 * 4; w += 256) {
        int posi = w >> 2, q = w & 3;
        int r, s;
        if (posi < 68) { r = (posi < 34) ? 0 : 33; s = posi % 34; }
        else { int e = posi - 68; r = 1 + (e >> 1); s = (e & 1) ? 33 : 0; }
        *(f16x8*)(base + ((size_t)r * 34 + s) * 32 + q * 8) = (f16x8){0, 0, 0, 0, 0, 0, 0, 0};
    }
}

// ---------------- conv4: padded 34x34x32 -> 64x64x1, fp32 out ----------------
__global__ __launch_bounds__(256) void conv4_kernel2(
    const __half* __restrict__ Xp, const __half* __restrict__ Wh,
    const float* __restrict__ bias, float* __restrict__ out) {
    int n = blockIdx.x;
    int t = threadIdx.x;
    int b = t & 31;
    int a = (blockIdx.y << 3) + (t >> 5);
    const __half* Xn = Xp + (size_t)n * 34 * 34 * 32;
    const f16x2* W2 = (const f16x2*)Wh;
    float a00 = 0.f, a01 = 0.f, a10 = 0.f, a11 = 0.f;
    #pragma unroll
    for (int hf = 0; hf < 2; ++hf) {
        f16x2 xw[9][8];
        #pragma unroll
        for (int u = 0; u < 3; ++u)
            #pragma unroll
            for (int v = 0; v < 3; ++v) {
                const f16x8* p = (const f16x8*)(Xn + ((size_t)(a + u) * 34 + (b + v)) * 32 + hf * 16);
                f16x8 lo = p[0], hi = p[1];
                #pragma unroll
                for (int e = 0; e < 4; ++e) {
                    xw[u * 3 + v][e]     = (f16x2){lo[2 * e], lo[2 * e + 1]};
                    xw[u * 3 + v][e + 4] = (f16x2){hi[2 * e], hi[2 * e + 1]};
                }
            }
        #pragma unroll
        for (int pi = 0; pi < 2; ++pi)
            #pragma unroll
            for (int pj = 0; pj < 2; ++pj) {
                float acc = pi ? (pj ? a11 : a10) : (pj ? a01 : a00);
                #pragma unroll
                for (int t1 = 0; t1 < 2; ++t1)
                    #pragma unroll
                    for (int t2 = 0; t2 < 2; ++t2) {
                        int pos = (pi + t1) * 3 + (pj + t2);
                        const f16x2* wrow = W2 + ((pi + 2 * t1) * 4 + (pj + 2 * t2)) * 16 + hf * 8;
                        #pragma unroll
                        for (int e = 0; e < 8; ++e)
                            acc = dot2f(xw[pos][e], wrow[e], acc);
                    }
                if (pi) { if (pj) a11 = acc; else a10 = acc; }
                else    { if (pj) a01 = acc; else a00 = acc; }
            }
    }
    float bv = bias[0];
    out[((size_t)n * 64 + 2 * a + 0) * 64 + 2 * b + 0] = a00 + bv;
    out[((size_t)n * 64 + 2 * a + 0) * 64 + 2 * b + 1] = a01 + bv;
    out[((size_t)n * 64 + 2 * a + 1) * 64 + 2 * b + 0] = a10 + bv;
    out[((size_t)n * 64 + 2 * a + 1) * 64 + 2 * b + 1] = a11 + bv;
}

// ---------------- launch -----------------------------------------------------
extern "C" void kernel_launch(void* const* d_in, const int* in_sizes, int n_in,
                              void* d_out, int out_size, void* d_ws, size_t ws_size,
                              hipStream_t stream) {
    const float* angles   = (const float*)d_in[0];
    const float* item_rep = (const float*)d_in[1];
    const float* W        = (const float*)d_in[2];
    const float* bfc      = (const float*)d_in[3];
    const float* k1       = (const float*)d_in[4];
    const float* b1       = (const float*)d_in[5];
    const float* k2       = (const float*)d_in[6];
    const float* b2       = (const float*)d_in[7];
    const float* k3       = (const float*)d_in[8];
    const float* b3       = (const float*)d_in[9];
    const float* k4       = (const float*)d_in[10];
    const float* b4       = (const float*)d_in[11];

    char* ws = (char*)d_ws;
    float*  Ctab  = (float*)(ws + 0);                 //  32 KB
    __half* itemh = (__half*)(ws + 32768);            //   2 MB
    __half* Bt1   = (__half*)(ws + 2129920);          //   1 MB
    __half* Bt2   = (__half*)(ws + 3178496);          // 256 KB
    __half* Bt3   = (__half*)(ws + 3440640);          //  64 KB
    __half* Kh4   = (__half*)(ws + 3506176);          //   1 KB
    __half* x0    = (__half*)(ws + 4194304);          //  16 MB -> 20,971,520
    __half* x1    = (__half*)(ws + 20971520);         //  32 MB -> 54,525,952
    __half* x3p   = (__half*)(ws + 4194304);          // 151.5 MB -> 155,713,536
    __half* Wtfc  = (__half*)(ws + 121634816);        //   4 MB (inside x3p, dead by conv3)
    __half* x2    = (__half*)(ws + 155713536);        //  64 MB -> 222,822,400
    float*  out   = (float*)d_out;

    coef_kernel<<<1, 512, 0, stream>>>(Ctab);
    wigner_kernel<<<NBATCH, 64, 0, stream>>>(angles, item_rep, Ctab, itemh);
    fcw_prep2<<<dim3(KPAD / 64, HID / 64), 256, 0, stream>>>(W, Wtfc);
    convw_prep<256, 128><<<16, 256, 0, stream>>>(k1, Bt1);
    convw_prep<128, 64><<<16, 256, 0, stream>>>(k2, Bt2);
    convw_prep<64, 32><<<16, 256, 0, stream>>>(k3, Bt3);
    conv4w_prep<<<2, 256, 0, stream>>>(k4, Kh4);

    // FC: 2048x512 @ 512x4096 -> x0
    fc_mfma<<<dim3(16, 32), 256, 0, stream>>>(itemh, Wtfc, bfc, x0);
    // conv1: 4x4x256 -> 8x8x128  (4 images/block, CF=2, 4 out-slices)
    convt_lds<256, 128, 4, 1, 2, 2, 4, 8, 0><<<dim3(512, 4), 256, 0, stream>>>(x0, Bt1, b1, x1);
    // conv2: 8x8x128 -> 16x16x64 (1 image/block, CF=4)
    convt_lds<128, 64, 8, 1, 3, 4, 4, 16, 0><<<dim3(2048, 1), 256, 0, stream>>>(x1, Bt2, b2, x2);
    // zero x3p border ring, then conv3 writes the 32x32 interior at +1
    pad_zero<<<NBATCH, 256, 0, stream>>>(x3p);
    // conv3: 16x16x64 -> (34x34 padded)x32 (1 image/block, 8 waves, R=2, CF=2)
    convt_lds<64, 32, 16, 2, 4, 2, 8, 34, 1><<<dim3(2048, 1), 512, 0, stream>>>(x2, Bt3, b3, x3p);
    // conv4: padded 34x34x32 -> 64x64x1 (fp32 out)
    conv4_kernel2<<<dim3(NBATCH, 4), 256, 0, stream>>>(x3p, Kh4, b4, out);
}